// Round 2
// baseline (278.558 us; speedup 1.0000x reference)
//
#include <hip/hip_runtime.h>
#include <hip/hip_bf16.h>

#define BSZ 2
#define QLEN 1024
#define KLEN 2048
#define HID 1024
#define NH 16
#define HD 64
#define SCALE 0.125f

using f32x4 = __attribute__((ext_vector_type(4))) float;
using bf16x8 = __attribute__((ext_vector_type(8))) short;   // 8 bf16 (4 VGPRs)
using u32x4 = __attribute__((ext_vector_type(4))) unsigned int;
using u32x2 = __attribute__((ext_vector_type(2))) unsigned int;

__device__ __forceinline__ unsigned short f2bf(float x) {
    unsigned int u = __builtin_bit_cast(unsigned int, x);
    u += 0x7FFFu + ((u >> 16) & 1u);          // round-to-nearest-even
    return (unsigned short)(u >> 16);
}
__device__ __forceinline__ unsigned int pack2bf(float a, float b) {
    return (unsigned int)f2bf(a) | ((unsigned int)f2bf(b) << 16);
}
__device__ __forceinline__ float sigm(float x) {
    return 1.0f / (1.0f + __expf(-x));
}
__device__ __forceinline__ f32x4 zero4() {
    f32x4 z = {0.0f, 0.0f, 0.0f, 0.0f};
    return z;
}

// ---------------------------------------------------------------------------
// Weight transpose + f32->bf16: W[K=1024][N=1024] f32  ->  Wt[N][K] bf16
// ---------------------------------------------------------------------------
__global__ __launch_bounds__(256) void wtrans_kernel(
    const float* __restrict__ W0, const float* __restrict__ W1,
    const float* __restrict__ W2, const float* __restrict__ W3,
    unsigned short* __restrict__ T0, unsigned short* __restrict__ T1,
    unsigned short* __restrict__ T2, unsigned short* __restrict__ T3)
{
    const float* W = blockIdx.z == 0 ? W0 : blockIdx.z == 1 ? W1 : blockIdx.z == 2 ? W2 : W3;
    unsigned short* T = blockIdx.z == 0 ? T0 : blockIdx.z == 1 ? T1 : blockIdx.z == 2 ? T2 : T3;
    __shared__ float tile[64][65];
    const int tid = threadIdx.x;
    const int r0 = blockIdx.x * 64;   // K dim
    const int c0 = blockIdx.y * 64;   // N dim
#pragma unroll
    for (int i = 0; i < 4; ++i) {
        int ch = i * 256 + tid;              // 1024 float4 chunks
        int row = ch >> 4, cg = ch & 15;
        float4 x = *(const float4*)&W[(size_t)(r0 + row) * 1024 + c0 + cg * 4];
        tile[row][cg * 4 + 0] = x.x;
        tile[row][cg * 4 + 1] = x.y;
        tile[row][cg * 4 + 2] = x.z;
        tile[row][cg * 4 + 3] = x.w;
    }
    __syncthreads();
#pragma unroll
    for (int i = 0; i < 2; ++i) {
        int ch = i * 256 + tid;              // 512 bf16x8 chunks
        int orow = ch >> 3, ocg = ch & 7;    // orow: N-local, ocg: K granule
        u32x4 o;
#pragma unroll
        for (int j = 0; j < 4; ++j)
            o[j] = pack2bf(tile[ocg * 8 + 2 * j][orow], tile[ocg * 8 + 2 * j + 1][orow]);
        *(u32x4*)&T[(size_t)(c0 + orow) * 1024 + r0 + ocg * 8] = o;
    }
}

// ---------------------------------------------------------------------------
// GEMM: C[M][N] = A[M][K] * B[K][N], B given as Bt[N][K] bf16.
// A is f32 (converted during staging) or bf16. 128x128 tile, BK=64, 4 waves.
// ---------------------------------------------------------------------------
template<bool AF32, bool OUTF32>
__global__ __launch_bounds__(256) void gemm_kernel(
    const void* __restrict__ Ap, const unsigned short* __restrict__ Bt,
    void* __restrict__ Cp, int M, int K, int N)
{
    __shared__ u32x4 AsBuf[128 * 64 / 8];
    __shared__ u32x4 BsBuf[128 * 64 / 8];
    unsigned short* As = (unsigned short*)AsBuf;
    unsigned short* Bs = (unsigned short*)BsBuf;

    const int tid = threadIdx.x;
    const int lane = tid & 63, wv = tid >> 6;
    const int wr = wv >> 1, wc = wv & 1;
    const int m = lane & 15, g = lane >> 4;
    const int m0 = blockIdx.x * 128, n0 = blockIdx.y * 128;

    f32x4 acc[4][4];
#pragma unroll
    for (int i = 0; i < 4; ++i)
#pragma unroll
        for (int j = 0; j < 4; ++j) acc[i][j] = zero4();

    for (int k0 = 0; k0 < K; k0 += 64) {
        // 128 rows x 64 cols bf16 per buffer = 8 chunks(16B) per row, 1024 chunks
#pragma unroll
        for (int c = 0; c < 4; ++c) {
            int idx = c * 256 + tid;
            int row = idx >> 3, cg = idx & 7;
            int s = (row * 64 + cg * 8) ^ ((row & 7) << 3);
            u32x4 wA;
            if constexpr (AF32) {
                const float* A = (const float*)Ap;
                const float* p = &A[(size_t)(m0 + row) * K + k0 + cg * 8];
                float4 x0 = *(const float4*)p;
                float4 x1 = *(const float4*)(p + 4);
                wA[0] = pack2bf(x0.x, x0.y); wA[1] = pack2bf(x0.z, x0.w);
                wA[2] = pack2bf(x1.x, x1.y); wA[3] = pack2bf(x1.z, x1.w);
            } else {
                const unsigned short* A = (const unsigned short*)Ap;
                wA = *(const u32x4*)&A[(size_t)(m0 + row) * K + k0 + cg * 8];
            }
            *(u32x4*)&As[s] = wA;
            u32x4 wB = *(const u32x4*)&Bt[(size_t)(n0 + row) * K + k0 + cg * 8];
            *(u32x4*)&Bs[s] = wB;
        }
        __syncthreads();
#pragma unroll
        for (int kk = 0; kk < 64; kk += 32) {
            bf16x8 af[4], bfr[4];
#pragma unroll
            for (int mi = 0; mi < 4; ++mi) {
                int row = wr * 64 + mi * 16 + m;
                af[mi] = *(const bf16x8*)&As[(row * 64 + kk + g * 8) ^ ((row & 7) << 3)];
            }
#pragma unroll
            for (int ni = 0; ni < 4; ++ni) {
                int row = wc * 64 + ni * 16 + m;
                bfr[ni] = *(const bf16x8*)&Bs[(row * 64 + kk + g * 8) ^ ((row & 7) << 3)];
            }
#pragma unroll
            for (int mi = 0; mi < 4; ++mi)
#pragma unroll
                for (int ni = 0; ni < 4; ++ni)
                    acc[mi][ni] = __builtin_amdgcn_mfma_f32_16x16x32_bf16(
                        af[mi], bfr[ni], acc[mi][ni], 0, 0, 0);
        }
        __syncthreads();
    }
    // epilogue: D layout col = lane&15, row = (lane>>4)*4 + reg
#pragma unroll
    for (int mi = 0; mi < 4; ++mi) {
#pragma unroll
        for (int r = 0; r < 4; ++r) {
            int row = m0 + wr * 64 + mi * 16 + g * 4 + r;
#pragma unroll
            for (int ni = 0; ni < 4; ++ni) {
                int col = n0 + wc * 64 + ni * 16 + m;
                float v = acc[mi][ni][r];
                if constexpr (OUTF32) ((float*)Cp)[(size_t)row * N + col] = v;
                else ((unsigned short*)Cp)[(size_t)row * N + col] = f2bf(v);
            }
        }
    }
}

// ---------------------------------------------------------------------------
// Fused sigmoid-attention.
// Grid: (QLEN/64, NH, BSZ), 4 waves; wave handles 16 q rows.
// S^T = K*Q^T (so P lands row-per-lane) -> mask*sigmoid -> per-wave LDS
// reshape of P into K=32 A-frag -> PV with V staged transposed in LDS.
// ---------------------------------------------------------------------------
__global__ __launch_bounds__(256) void attn_kernel(
    const unsigned short* __restrict__ hq, const unsigned short* __restrict__ hk,
    const unsigned short* __restrict__ hv, const int* __restrict__ amask,
    unsigned short* __restrict__ av)
{
    __shared__ u32x4 KsBuf[64 * 64 / 8];
    __shared__ u32x4 VsBuf[64 * 64 / 8];   // transposed: [d][kv]
    __shared__ float Ml[64];
    __shared__ u32x4 PsBuf[4][16 * 32 / 8]; // per-wave P[16 i][32 j]
    unsigned short* Ks = (unsigned short*)KsBuf;
    unsigned short* Vs = (unsigned short*)VsBuf;

    const int tid = threadIdx.x;
    const int lane = tid & 63, wv = tid >> 6;
    const int m = lane & 15, g = lane >> 4;
    const int qt = blockIdx.x, h = blockIdx.y, b = blockIdx.z;
    const int qrow0 = qt * 64 + wv * 16;
    unsigned short* Pw = (unsigned short*)PsBuf[wv];

    // Q fragments (also valid as B-operand for S^T = K*Q^T)
    const unsigned short* qp = &hq[(size_t)(b * QLEN + qrow0 + m) * HID + h * HD + g * 8];
    bf16x8 qf[2];
    qf[0] = *(const bf16x8*)qp;
    qf[1] = *(const bf16x8*)(qp + 32);

    f32x4 o[4];
#pragma unroll
    for (int i = 0; i < 4; ++i) o[i] = zero4();

    for (int kv0 = 0; kv0 < KLEN; kv0 += 64) {
        // stage K [64 kv][64 d] bf16: 8 chunks(16B) per row, 512 chunks
#pragma unroll
        for (int c = 0; c < 2; ++c) {
            int idx = c * 256 + tid;
            int row = idx >> 3, cg = idx & 7;
            u32x4 x = *(const u32x4*)&hk[(size_t)(b * KLEN + kv0 + row) * HID + h * HD + cg * 8];
            *(u32x4*)&Ks[(row * 64 + cg * 8) ^ ((row & 7) << 3)] = x;
        }
        // stage V transposed: Vs[d][kv], swizzle by ((d>>3)^d)&7
#pragma unroll
        for (int c = 0; c < 2; ++c) {
            int idx = c * 256 + tid;
            int kvr = idx >> 3, dg = idx & 7;
            u32x4 x = *(const u32x4*)&hv[(size_t)(b * KLEN + kv0 + kvr) * HID + h * HD + dg * 8];
            const unsigned short* e = (const unsigned short*)&x;
#pragma unroll
            for (int j = 0; j < 8; ++j) {
                int d = dg * 8 + j;
                Vs[(d * 64 + kvr) ^ ((((d >> 3) ^ d) & 7) << 3)] = e[j];
            }
        }
        if (tid < 64) Ml[tid] = (amask[b * KLEN + kv0 + tid] != 0) ? 1.0f : 0.0f;
        __syncthreads();

#pragma unroll
        for (int sub = 0; sub < 2; ++sub) {
#pragma unroll
            for (int t = 0; t < 2; ++t) {
                int kvr = sub * 32 + t * 16 + m;          // A-frag row = lane&15
                bf16x8 ak0 = *(const bf16x8*)&Ks[(kvr * 64 + g * 8) ^ ((kvr & 7) << 3)];
                bf16x8 ak1 = *(const bf16x8*)&Ks[(kvr * 64 + 32 + g * 8) ^ ((kvr & 7) << 3)];
                f32x4 s = zero4();
                s = __builtin_amdgcn_mfma_f32_16x16x32_bf16(ak0, qf[0], s, 0, 0, 0);
                s = __builtin_amdgcn_mfma_f32_16x16x32_bf16(ak1, qf[1], s, 0, 0, 0);
                // lane holds S^T[kv-local = t*16 + 4g + r][q = m]
                f32x4 mk = *(const f32x4*)&Ml[sub * 32 + t * 16 + 4 * g];
                float p0 = mk[0] * sigm(s[0] * SCALE);
                float p1 = mk[1] * sigm(s[1] * SCALE);
                float p2 = mk[2] * sigm(s[2] * SCALE);
                float p3 = mk[3] * sigm(s[3] * SCALE);
                u32x2 pp = { pack2bf(p0, p1), pack2bf(p2, p3) };
                *(u32x2*)&Pw[m * 32 + t * 16 + 4 * g] = pp;   // P[q=m][j-local]
            }
            // A-frag of P: lane reads P[q=m][8g..8g+7] (same-wave LDS, no barrier)
            bf16x8 pa = *(const bf16x8*)&Pw[m * 32 + 8 * g];
#pragma unroll
            for (int nt = 0; nt < 4; ++nt) {
                int d = 16 * nt + m;
                bf16x8 vt = *(const bf16x8*)&Vs[(d * 64 + sub * 32 + 8 * g) ^ ((((d >> 3) ^ d) & 7) << 3)];
                o[nt] = __builtin_amdgcn_mfma_f32_16x16x32_bf16(pa, vt, o[nt], 0, 0, 0);
            }
        }
        __syncthreads();
    }
    // O layout: lane reg r holds O[q = 4g+r][d = 16nt+m]
#pragma unroll
    for (int nt = 0; nt < 4; ++nt)
#pragma unroll
        for (int r = 0; r < 4; ++r)
            av[(size_t)(b * QLEN + qrow0 + 4 * g + r) * HID + h * HD + 16 * nt + m] =
                f2bf(o[nt][r]);
}

// ---------------------------------------------------------------------------
extern "C" void kernel_launch(void* const* d_in, const int* in_sizes, int n_in,
                              void* d_out, int out_size, void* d_ws, size_t ws_size,
                              hipStream_t stream)
{
    const float* query = (const float*)d_in[0];
    const float* key   = (const float*)d_in[1];
    const float* value = (const float*)d_in[2];
    const int*   amask = (const int*)d_in[3];
    const float* Wq    = (const float*)d_in[4];
    const float* Wk    = (const float*)d_in[5];
    const float* Wv    = (const float*)d_in[6];
    const float* Wo    = (const float*)d_in[7];

    char* ws = (char*)d_ws;
    unsigned short* wtq = (unsigned short*)(ws + (0ull  << 20));
    unsigned short* wtk = (unsigned short*)(ws + (2ull  << 20));
    unsigned short* wtv = (unsigned short*)(ws + (4ull  << 20));
    unsigned short* wto = (unsigned short*)(ws + (6ull  << 20));
    unsigned short* hq  = (unsigned short*)(ws + (8ull  << 20));
    unsigned short* hk  = (unsigned short*)(ws + (12ull << 20));
    unsigned short* hv  = (unsigned short*)(ws + (20ull << 20));
    unsigned short* av  = (unsigned short*)(ws + (28ull << 20));

    wtrans_kernel<<<dim3(16, 16, 4), 256, 0, stream>>>(Wq, Wk, Wv, Wo, wtq, wtk, wtv, wto);
    gemm_kernel<true,  false><<<dim3(16, 8), 256, 0, stream>>>(query, wtq, hq, BSZ * QLEN, HID, HID);
    gemm_kernel<true,  false><<<dim3(32, 8), 256, 0, stream>>>(key,   wtk, hk, BSZ * KLEN, HID, HID);
    gemm_kernel<true,  false><<<dim3(32, 8), 256, 0, stream>>>(value, wtv, hv, BSZ * KLEN, HID, HID);
    attn_kernel<<<dim3(QLEN / 64, NH, BSZ), 256, 0, stream>>>(hq, hk, hv, amask, av);
    gemm_kernel<false, true ><<<dim3(16, 8), 256, 0, stream>>>(av, wto, d_out, BSZ * QLEN, HID, HID);
}

// Round 7
// 256.632 us; speedup vs baseline: 1.0854x; 1.0854x over previous
//
#include <hip/hip_runtime.h>
#include <hip/hip_bf16.h>

#define BSZ 2
#define QLEN 1024
#define KLEN 2048
#define HID 1024
#define NH 16
#define HD 64
#define SCALE 0.125f

using f32x4 = __attribute__((ext_vector_type(4))) float;
using bf16x8 = __attribute__((ext_vector_type(8))) short;   // 8 bf16 (4 VGPRs)
using u32x4 = __attribute__((ext_vector_type(4))) unsigned int;
using u32x2 = __attribute__((ext_vector_type(2))) unsigned int;
typedef unsigned short u16;

__device__ __forceinline__ u16 f2bf(float x) {
    unsigned int u = __builtin_bit_cast(unsigned int, x);
    u += 0x7FFFu + ((u >> 16) & 1u);          // round-to-nearest-even
    return (u16)(u >> 16);
}
__device__ __forceinline__ unsigned int pack2bf(float a, float b) {
    return (unsigned int)f2bf(a) | ((unsigned int)f2bf(b) << 16);
}
__device__ __forceinline__ float sigm(float x) {
    return 1.0f / (1.0f + __expf(-x));
}
__device__ __forceinline__ f32x4 zero4() {
    f32x4 z = {0.0f, 0.0f, 0.0f, 0.0f};
    return z;
}

// async global->LDS, 16B per lane
__device__ __forceinline__ void gl16(const void* g, void* l) {
    __builtin_amdgcn_global_load_lds(
        (const __attribute__((address_space(1))) void*)g,
        (__attribute__((address_space(3))) void*)l, 16, 0, 0);
}

// Stage a [ROWS][64] bf16 tile (row stride gstride elems) into linear LDS via
// global_load_lds, with source pre-swizzle so LDS slot s of row r holds global
// granule s ^ (r&7). Read back granule gg at element ((r*64+gg*8) ^ ((r&7)<<3)).
template<int ROWS>
__device__ __forceinline__ void stage64(const u16* __restrict__ g, size_t gstride,
                                        u16* lds, int tid) {
    const int lane = tid & 63, wv = tid >> 6;
    constexpr int RPW = ROWS / 4;        // rows per wave
#pragma unroll
    for (int c = 0; c < RPW / 8; ++c) {
        int row = wv * RPW + c * 8 + (lane >> 3);
        int cg = (lane & 7) ^ (row & 7);
        gl16(g + (size_t)row * gstride + cg * 8, lds + (size_t)(wv * RPW + c * 8) * 64);
    }
}

// ---------------------------------------------------------------------------
// Weight transpose + f32->bf16: W[K=1024][N=1024] f32  ->  Wt[N][K] bf16
// ---------------------------------------------------------------------------
__global__ __launch_bounds__(256) void wtrans_kernel(
    const float* __restrict__ W0, const float* __restrict__ W1,
    const float* __restrict__ W2, const float* __restrict__ W3,
    u16* __restrict__ T0, u16* __restrict__ T1,
    u16* __restrict__ T2, u16* __restrict__ T3)
{
    const float* W = blockIdx.z == 0 ? W0 : blockIdx.z == 1 ? W1 : blockIdx.z == 2 ? W2 : W3;
    u16* T = blockIdx.z == 0 ? T0 : blockIdx.z == 1 ? T1 : blockIdx.z == 2 ? T2 : T3;
    __shared__ float tile[64][65];
    const int tid = threadIdx.x;
    const int r0 = blockIdx.x * 64;   // K dim
    const int c0 = blockIdx.y * 64;   // N dim
#pragma unroll
    for (int i = 0; i < 4; ++i) {
        int ch = i * 256 + tid;
        int row = ch >> 4, cg = ch & 15;
        float4 x = *(const float4*)&W[(size_t)(r0 + row) * 1024 + c0 + cg * 4];
        tile[row][cg * 4 + 0] = x.x;
        tile[row][cg * 4 + 1] = x.y;
        tile[row][cg * 4 + 2] = x.z;
        tile[row][cg * 4 + 3] = x.w;
    }
    __syncthreads();
#pragma unroll
    for (int i = 0; i < 2; ++i) {
        int ch = i * 256 + tid;
        int orow = ch >> 3, ocg = ch & 7;
        u32x4 o;
#pragma unroll
        for (int j = 0; j < 4; ++j)
            o[j] = pack2bf(tile[ocg * 8 + 2 * j][orow], tile[ocg * 8 + 2 * j + 1][orow]);
        *(u32x4*)&T[(size_t)(c0 + orow) * 1024 + r0 + ocg * 8] = o;
    }
}

// ---------------------------------------------------------------------------
// Fused QKV projection GEMM. blocks 0..127: Q (M=2048), 128..383: K (M=4096),
// 384..639: V (M=4096). 128x128 tile, BK=64, 4 waves.
// A f32 reg-staged (converted to bf16); B bf16 via global_load_lds.
// V task writes TRANSPOSED output hvT[b*HID + ch][KLEN] via LDS transpose.
// ---------------------------------------------------------------------------
__global__ __launch_bounds__(256) void qkv_gemm_kernel(
    const float* __restrict__ Aq, const float* __restrict__ Ak, const float* __restrict__ Av,
    const u16* __restrict__ Bq, const u16* __restrict__ Bk, const u16* __restrict__ Bv,
    u16* __restrict__ hq, u16* __restrict__ hk, u16* __restrict__ hvT)
{
    __shared__ u32x4 lds[2048];              // 32KB: As 16KB | Bs 16KB
    u16* As = (u16*)lds;
    u16* Bs = (u16*)(lds + 1024);

    const int bid = blockIdx.x;
    const float* A; const u16* Bt; u16* C; int lb, task;
    if (bid < 128)      { task = 0; A = Aq; Bt = Bq; C = hq; lb = bid; }
    else if (bid < 384) { task = 1; A = Ak; Bt = Bk; C = hk; lb = bid - 128; }
    else                { task = 2; A = Av; Bt = Bv; C = nullptr; lb = bid - 384; }
    const int m0 = (lb >> 3) * 128, n0 = (lb & 7) * 128;

    const int tid = threadIdx.x;
    const int lane = tid & 63, wv = tid >> 6;
    const int wr = wv >> 1, wc = wv & 1;
    const int m = lane & 15, g = lane >> 4;

    f32x4 acc[4][4];
#pragma unroll
    for (int i = 0; i < 4; ++i)
#pragma unroll
        for (int j = 0; j < 4; ++j) acc[i][j] = zero4();

    for (int k0 = 0; k0 < 1024; k0 += 64) {
        // B: async DMA with pre-swizzled source
        stage64<128>(Bt + (size_t)n0 * 1024 + k0, 1024, Bs, tid);
        // A: reg-staged f32->bf16, swizzled LDS write
#pragma unroll
        for (int c = 0; c < 4; ++c) {
            int idx = c * 256 + tid;
            int row = idx >> 3, cg = idx & 7;
            const float* p = &A[(size_t)(m0 + row) * 1024 + k0 + cg * 8];
            float4 x0 = *(const float4*)p;
            float4 x1 = *(const float4*)(p + 4);
            u32x4 w;
            w[0] = pack2bf(x0.x, x0.y); w[1] = pack2bf(x0.z, x0.w);
            w[2] = pack2bf(x1.x, x1.y); w[3] = pack2bf(x1.z, x1.w);
            *(u32x4*)&As[(row * 64 + cg * 8) ^ ((row & 7) << 3)] = w;
        }
        __syncthreads();
#pragma unroll
        for (int kk = 0; kk < 64; kk += 32) {
            bf16x8 af[4], bfr[4];
#pragma unroll
            for (int mi = 0; mi < 4; ++mi) {
                int row = wr * 64 + mi * 16 + m;
                af[mi] = *(const bf16x8*)&As[(row * 64 + kk + g * 8) ^ ((row & 7) << 3)];
            }
#pragma unroll
            for (int ni = 0; ni < 4; ++ni) {
                int row = wc * 64 + ni * 16 + m;
                bfr[ni] = *(const bf16x8*)&Bs[(row * 64 + kk + g * 8) ^ ((row & 7) << 3)];
            }
#pragma unroll
            for (int mi = 0; mi < 4; ++mi)
#pragma unroll
                for (int ni = 0; ni < 4; ++ni)
                    acc[mi][ni] = __builtin_amdgcn_mfma_f32_16x16x32_bf16(
                        af[mi], bfr[ni], acc[mi][ni], 0, 0, 0);
        }
        __syncthreads();
    }

    if (task < 2) {
        // normal epilogue: C[row][HID] bf16
#pragma unroll
        for (int mi = 0; mi < 4; ++mi)
#pragma unroll
            for (int r = 0; r < 4; ++r) {
                int row = m0 + wr * 64 + mi * 16 + g * 4 + r;
#pragma unroll
                for (int ni = 0; ni < 4; ++ni) {
                    int col = n0 + wc * 64 + ni * 16 + m;
                    C[(size_t)row * HID + col] = f2bf(acc[mi][ni][r]);
                }
            }
    } else {
        // transposed epilogue -> hvT[b*HID + ch][KLEN]
        // T[ch][kv] with kv-granule swizzle: granule gg of col ch stored at
        // slot gg ^ (ch&7); within-granule offset = kv&7.
        u16* T = (u16*)lds;                  // 128(ch) x 128(kv) bf16 = 32KB
#pragma unroll
        for (int mi = 0; mi < 4; ++mi)
#pragma unroll
            for (int ni = 0; ni < 4; ++ni)
#pragma unroll
                for (int r = 0; r < 4; ++r) {
                    int row = wr * 64 + mi * 16 + g * 4 + r;   // kv-local
                    int col = wc * 64 + ni * 16 + m;           // ch-local
                    T[col * 128 + ((((row >> 3) ^ (col & 7)) << 3) + (row & 7))] =
                        f2bf(acc[mi][ni][r]);
                }
        __syncthreads();
        const int b = m0 >> 11, kv0 = m0 & 2047;
        // 128 rows x 16 granules = 2048 chunks of 16B
#pragma unroll
        for (int it = 0; it < 8; ++it) {
            int idx = it * 256 + tid;
            int orow = idx >> 4, og = idx & 15;
            u32x4 x = *(const u32x4*)&T[orow * 128 + ((og ^ (orow & 7)) << 3)];
            *(u32x4*)&hvT[(size_t)(b * HID + n0 + orow) * KLEN + kv0 + og * 8] = x;
        }
    }
}

// ---------------------------------------------------------------------------
// Fused sigmoid-attention, kv-split = 2.
// Grid (16 qt, 16 h, 4 = b*2+split), 4 waves; wave owns 16 q rows x 1024 kv.
// K and V^T tiles staged via global_load_lds (pre-swizzled source).
// Output: f32 partial O into O0/O1.
// ---------------------------------------------------------------------------
__global__ __launch_bounds__(256) void attn_kernel(
    const u16* __restrict__ hq, const u16* __restrict__ hk,
    const u16* __restrict__ hvT, const int* __restrict__ amask,
    float* __restrict__ O0, float* __restrict__ O1)
{
    __shared__ u32x4 KsBuf[512];             // 8KB
    __shared__ u32x4 VtBuf[512];             // 8KB
    __shared__ __align__(16) float Ml[64];
    __shared__ __align__(16) u16 Pw[4][16 * 40];  // padded stride 40
    u16* Ks = (u16*)KsBuf;
    u16* Vt = (u16*)VtBuf;

    const int tid = threadIdx.x;
    const int lane = tid & 63, wv = tid >> 6;
    const int m = lane & 15, g = lane >> 4;
    const int qt = blockIdx.x, h = blockIdx.y;
    const int b = blockIdx.z >> 1, sp = blockIdx.z & 1;
    const int qrow0 = qt * 64 + wv * 16;
    float* Op = sp ? O1 : O0;
    u16* P = Pw[wv];

    const u16* qp = &hq[(size_t)(b * QLEN + qrow0 + m) * HID + h * HD + g * 8];
    bf16x8 qf0 = *(const bf16x8*)qp;
    bf16x8 qf1 = *(const bf16x8*)(qp + 32);

    const u16* kbase = hk + (size_t)(b * KLEN + sp * 1024) * HID + h * HD;
    const u16* vbase = hvT + (size_t)(b * HID + h * HD) * KLEN + sp * 1024;
    const int* mbase = amask + b * KLEN + sp * 1024;

    f32x4 o[4];
#pragma unroll
    for (int i = 0; i < 4; ++i) o[i] = zero4();

    for (int kv0 = 0; kv0 < 1024; kv0 += 64) {
        stage64<64>(kbase + (size_t)kv0 * HID, HID, Ks, tid);
        stage64<64>(vbase + kv0, KLEN, Vt, tid);
        if (tid < 64) Ml[tid] = (mbase[kv0 + tid] != 0) ? 1.0f : 0.0f;
        __syncthreads();

#pragma unroll
        for (int sub = 0; sub < 2; ++sub) {
#pragma unroll
            for (int t = 0; t < 2; ++t) {
                int kvr = sub * 32 + t * 16 + m;
                bf16x8 ak0 = *(const bf16x8*)&Ks[(kvr * 64 + g * 8) ^ ((kvr & 7) << 3)];
                bf16x8 ak1 = *(const bf16x8*)&Ks[(kvr * 64 + 32 + g * 8) ^ ((kvr & 7) << 3)];
                f32x4 s = zero4();
                s = __builtin_amdgcn_mfma_f32_16x16x32_bf16(ak0, qf0, s, 0, 0, 0);
                s = __builtin_amdgcn_mfma_f32_16x16x32_bf16(ak1, qf1, s, 0, 0, 0);
                // lane holds S^T[kv = sub*32 + t*16 + 4g + r][q = m]
                f32x4 mk = *(const f32x4*)&Ml[sub * 32 + t * 16 + 4 * g];
                float p0 = mk[0] * sigm(s[0] * SCALE);
                float p1 = mk[1] * sigm(s[1] * SCALE);
                float p2 = mk[2] * sigm(s[2] * SCALE);
                float p3 = mk[3] * sigm(s[3] * SCALE);
                u32x2 pp = { pack2bf(p0, p1), pack2bf(p2, p3) };
                *(u32x2*)&P[m * 40 + t * 16 + 4 * g] = pp;    // P[q=m][j-local]
            }
            // same-wave roundtrip: lane reads P[q=m][8g..8g+7]
            bf16x8 pa = *(const bf16x8*)&P[m * 40 + 8 * g];
#pragma unroll
            for (int nt = 0; nt < 4; ++nt) {
                int d = 16 * nt + m;
                bf16x8 vt = *(const bf16x8*)&Vt[(d * 64 + sub * 32 + g * 8) ^ ((d & 7) << 3)];
                o[nt] = __builtin_amdgcn_mfma_f32_16x16x32_bf16(pa, vt, o[nt], 0, 0, 0);
            }
        }
        __syncthreads();
    }
    // lane reg r holds O[q = 4g+r][d = 16nt+m]
#pragma unroll
    for (int nt = 0; nt < 4; ++nt)
#pragma unroll
        for (int r = 0; r < 4; ++r)
            Op[(size_t)(b * QLEN + qrow0 + 4 * g + r) * HID + h * HD + 16 * nt + m] =
                o[nt][r];
}

// ---------------------------------------------------------------------------
// Output projection: out = (O0+O1) @ Wo. 128x64 tile, 256 blocks, f32 out.
// ---------------------------------------------------------------------------
__global__ __launch_bounds__(256) void oproj_kernel(
    const float* __restrict__ O0, const float* __restrict__ O1,
    const u16* __restrict__ Bt, float* __restrict__ out)
{
    __shared__ u32x4 lds[1536];              // As 16KB | Bs 8KB
    u16* As = (u16*)lds;
    u16* Bs = (u16*)(lds + 1024);

    const int tid = threadIdx.x;
    const int lane = tid & 63, wv = tid >> 6;
    const int wr = wv >> 1, wc = wv & 1;
    const int m = lane & 15, g = lane >> 4;
    const int m0 = blockIdx.x * 128, n0 = blockIdx.y * 64;

    f32x4 acc[4][2];
#pragma unroll
    for (int i = 0; i < 4; ++i)
#pragma unroll
        for (int j = 0; j < 2; ++j) acc[i][j] = zero4();

    for (int k0 = 0; k0 < 1024; k0 += 64) {
        stage64<64>(Bt + (size_t)n0 * 1024 + k0, 1024, Bs, tid);
#pragma unroll
        for (int c = 0; c < 4; ++c) {
            int idx = c * 256 + tid;
            int row = idx >> 3, cg = idx & 7;
            size_t off = (size_t)(m0 + row) * 1024 + k0 + cg * 8;
            float4 a0 = *(const float4*)&O0[off];
            float4 a1 = *(const float4*)&O0[off + 4];
            float4 b0 = *(const float4*)&O1[off];
            float4 b1 = *(const float4*)&O1[off + 4];
            u32x4 w;
            w[0] = pack2bf(a0.x + b0.x, a0.y + b0.y);
            w[1] = pack2bf(a0.z + b0.z, a0.w + b0.w);
            w[2] = pack2bf(a1.x + b1.x, a1.y + b1.y);
            w[3] = pack2bf(a1.z + b1.z, a1.w + b1.w);
            *(u32x4*)&As[(row * 64 + cg * 8) ^ ((row & 7) << 3)] = w;
        }
        __syncthreads();
#pragma unroll
        for (int kk = 0; kk < 64; kk += 32) {
            bf16x8 af[4], bfr[2];
#pragma unroll
            for (int mi = 0; mi < 4; ++mi) {
                int row = wr * 64 + mi * 16 + m;
                af[mi] = *(const bf16x8*)&As[(row * 64 + kk + g * 8) ^ ((row & 7) << 3)];
            }
#pragma unroll
            for (int ni = 0; ni < 2; ++ni) {
                int row = wc * 32 + ni * 16 + m;
                bfr[ni] = *(const bf16x8*)&Bs[(row * 64 + kk + g * 8) ^ ((row & 7) << 3)];
            }
#pragma unroll
            for (int mi = 0; mi < 4; ++mi)
#pragma unroll
                for (int ni = 0; ni < 2; ++ni)
                    acc[mi][ni] = __builtin_amdgcn_mfma_f32_16x16x32_bf16(
                        af[mi], bfr[ni], acc[mi][ni], 0, 0, 0);
        }
        __syncthreads();
    }
#pragma unroll
    for (int mi = 0; mi < 4; ++mi)
#pragma unroll
        for (int r = 0; r < 4; ++r) {
            int row = m0 + wr * 64 + mi * 16 + g * 4 + r;
#pragma unroll
            for (int ni = 0; ni < 2; ++ni) {
                int col = n0 + wc * 32 + ni * 16 + m;
                out[(size_t)row * HID + col] = acc[mi][ni][r];
            }
        }
}

// ---------------------------------------------------------------------------
extern "C" void kernel_launch(void* const* d_in, const int* in_sizes, int n_in,
                              void* d_out, int out_size, void* d_ws, size_t ws_size,
                              hipStream_t stream)
{
    const float* query = (const float*)d_in[0];
    const float* key   = (const float*)d_in[1];
    const float* value = (const float*)d_in[2];
    const int*   amask = (const int*)d_in[3];
    const float* Wq    = (const float*)d_in[4];
    const float* Wk    = (const float*)d_in[5];
    const float* Wv    = (const float*)d_in[6];
    const float* Wo    = (const float*)d_in[7];

    char* ws = (char*)d_ws;
    u16* wtq = (u16*)(ws + (0ull  << 20));   // 2MB
    u16* wtk = (u16*)(ws + (2ull  << 20));   // 2MB
    u16* wtv = (u16*)(ws + (4ull  << 20));   // 2MB
    u16* wto = (u16*)(ws + (6ull  << 20));   // 2MB
    u16* hq  = (u16*)(ws + (8ull  << 20));   // 4MB  bf16 [2048][1024]
    u16* hk  = (u16*)(ws + (12ull << 20));   // 8MB  bf16 [4096][1024]
    u16* hvT = (u16*)(ws + (20ull << 20));   // 8MB  bf16 [2048][2048] (b*HID+ch, kv)
    float* O0 = (float*)(ws + (28ull << 20)); // 8MB f32 [2048][1024]
    float* O1 = (float*)(ws + (36ull << 20)); // 8MB

    wtrans_kernel<<<dim3(16, 16, 4), 256, 0, stream>>>(Wq, Wk, Wv, Wo, wtq, wtk, wtv, wto);
    qkv_gemm_kernel<<<dim3(640), 256, 0, stream>>>(query, key, value, wtq, wtk, wtv, hq, hk, hvT);
    attn_kernel<<<dim3(16, 16, 4), 256, 0, stream>>>(hq, hk, hvT, amask, O0, O1);
    oproj_kernel<<<dim3(16, 16), 256, 0, stream>>>(O0, O1, wto, (float*)d_out);
}

// Round 8
// 223.653 us; speedup vs baseline: 1.2455x; 1.1475x over previous
//
#include <hip/hip_runtime.h>
#include <hip/hip_bf16.h>

#define BSZ 2
#define QLEN 1024
#define KLEN 2048
#define HID 1024
#define NH 16
#define HD 64
#define SCALE 0.125f

using f32x4 = __attribute__((ext_vector_type(4))) float;
using bf16x8 = __attribute__((ext_vector_type(8))) short;   // 8 bf16 (4 VGPRs)
using u32x4 = __attribute__((ext_vector_type(4))) unsigned int;
using u32x2 = __attribute__((ext_vector_type(2))) unsigned int;
typedef unsigned short u16;

__device__ __forceinline__ u16 f2bf(float x) {
    unsigned int u = __builtin_bit_cast(unsigned int, x);
    u += 0x7FFFu + ((u >> 16) & 1u);          // round-to-nearest-even
    return (u16)(u >> 16);
}
__device__ __forceinline__ unsigned int pack2bf(float a, float b) {
    return (unsigned int)f2bf(a) | ((unsigned int)f2bf(b) << 16);
}
__device__ __forceinline__ float sigm(float x) {
    return 1.0f / (1.0f + __expf(-x));
}
__device__ __forceinline__ f32x4 zero4() {
    f32x4 z = {0.0f, 0.0f, 0.0f, 0.0f};
    return z;
}

// async global->LDS, 16B per lane
__device__ __forceinline__ void gl16(const void* g, void* l) {
    __builtin_amdgcn_global_load_lds(
        (const __attribute__((address_space(1))) void*)g,
        (__attribute__((address_space(3))) void*)l, 16, 0, 0);
}

// Stage a [ROWS][64] bf16 tile (row stride gstride elems) into linear LDS via
// global_load_lds, with source pre-swizzle so LDS slot s of row r holds global
// granule s ^ (r&7). Read back granule gg at element ((r*64+gg*8) ^ ((r&7)<<3)).
template<int ROWS>
__device__ __forceinline__ void stage64(const u16* __restrict__ g, size_t gstride,
                                        u16* lds, int tid) {
    const int lane = tid & 63, wv = tid >> 6;
    constexpr int RPW = ROWS / 4;        // rows per wave
#pragma unroll
    for (int c = 0; c < RPW / 8; ++c) {
        int row = wv * RPW + c * 8 + (lane >> 3);
        int cg = (lane & 7) ^ (row & 7);
        gl16(g + (size_t)row * gstride + cg * 8, lds + (size_t)(wv * RPW + c * 8) * 64);
    }
}

// ---------------------------------------------------------------------------
// f32 -> bf16 conversion of query/key/value activations (one-shot).
// 5120 blocks x 256 threads x 8 elems: 0..1023 query, 1024..3071 key, rest value.
// ---------------------------------------------------------------------------
__global__ __launch_bounds__(256) void a2bf_kernel(
    const float* __restrict__ Aq, const float* __restrict__ Ak,
    const float* __restrict__ Av,
    u16* __restrict__ qbf, u16* __restrict__ kbf, u16* __restrict__ vbf)
{
    const int bid = blockIdx.x;
    const float* src; u16* dst; size_t base;
    if (bid < 1024)      { src = Aq; dst = qbf; base = (size_t)bid * 2048; }
    else if (bid < 3072) { src = Ak; dst = kbf; base = (size_t)(bid - 1024) * 2048; }
    else                 { src = Av; dst = vbf; base = (size_t)(bid - 3072) * 2048; }
    size_t e = base + (size_t)threadIdx.x * 8;
    float4 x0 = *(const float4*)&src[e];
    float4 x1 = *(const float4*)&src[e + 4];
    u32x4 w;
    w[0] = pack2bf(x0.x, x0.y); w[1] = pack2bf(x0.z, x0.w);
    w[2] = pack2bf(x1.x, x1.y); w[3] = pack2bf(x1.z, x1.w);
    *(u32x4*)&dst[e] = w;
}

// ---------------------------------------------------------------------------
// Weight transpose + f32->bf16: W[K=1024][N=1024] f32  ->  Wt[N][K] bf16
// ---------------------------------------------------------------------------
__global__ __launch_bounds__(256) void wtrans_kernel(
    const float* __restrict__ W0, const float* __restrict__ W1,
    const float* __restrict__ W2, const float* __restrict__ W3,
    u16* __restrict__ T0, u16* __restrict__ T1,
    u16* __restrict__ T2, u16* __restrict__ T3)
{
    const float* W = blockIdx.z == 0 ? W0 : blockIdx.z == 1 ? W1 : blockIdx.z == 2 ? W2 : W3;
    u16* T = blockIdx.z == 0 ? T0 : blockIdx.z == 1 ? T1 : blockIdx.z == 2 ? T2 : T3;
    __shared__ float tile[64][65];
    const int tid = threadIdx.x;
    const int r0 = blockIdx.x * 64;   // K dim
    const int c0 = blockIdx.y * 64;   // N dim
#pragma unroll
    for (int i = 0; i < 4; ++i) {
        int ch = i * 256 + tid;
        int row = ch >> 4, cg = ch & 15;
        float4 x = *(const float4*)&W[(size_t)(r0 + row) * 1024 + c0 + cg * 4];
        tile[row][cg * 4 + 0] = x.x;
        tile[row][cg * 4 + 1] = x.y;
        tile[row][cg * 4 + 2] = x.z;
        tile[row][cg * 4 + 3] = x.w;
    }
    __syncthreads();
#pragma unroll
    for (int i = 0; i < 2; ++i) {
        int ch = i * 256 + tid;
        int orow = ch >> 3, ocg = ch & 7;
        u32x4 o;
#pragma unroll
        for (int j = 0; j < 4; ++j)
            o[j] = pack2bf(tile[ocg * 8 + 2 * j][orow], tile[ocg * 8 + 2 * j + 1][orow]);
        *(u32x4*)&T[(size_t)(c0 + orow) * 1024 + r0 + ocg * 8] = o;
    }
}

// ---------------------------------------------------------------------------
// Fused QKV projection GEMM, all-bf16, both operands via global_load_lds.
// bid 0..127: Q (M=2048), 128..383: K (M=4096), 384..639: V (M=4096).
// 128x128 tile, BK=64, 4 waves. XCD-swizzled block order: the 8 n-blocks of
// one A-panel land on one XCD (L2 A-reuse).
// V task writes TRANSPOSED output hvT[b*HID + ch][KLEN] via LDS transpose.
// ---------------------------------------------------------------------------
__global__ __launch_bounds__(256) void qkv_gemm_kernel(
    const u16* __restrict__ Aq, const u16* __restrict__ Ak, const u16* __restrict__ Av,
    const u16* __restrict__ Bq, const u16* __restrict__ Bk, const u16* __restrict__ Bv,
    u16* __restrict__ hq, u16* __restrict__ hk, u16* __restrict__ hvT)
{
    __shared__ u32x4 lds[2048];              // 32KB: As 16KB | Bs 16KB
    u16* As = (u16*)lds;
    u16* Bs = (u16*)(lds + 1024);

    const int i = blockIdx.x;                // 640 blocks
    const int bid = (i & 7) * 80 + (i >> 3); // XCD-contiguous chunks of 80
    const u16* A; const u16* Bt; u16* C; int lb, task;
    if (bid < 128)      { task = 0; A = Aq; Bt = Bq; C = hq; lb = bid; }
    else if (bid < 384) { task = 1; A = Ak; Bt = Bk; C = hk; lb = bid - 128; }
    else                { task = 2; A = Av; Bt = Bv; C = nullptr; lb = bid - 384; }
    const int m0 = (lb >> 3) * 128, n0 = (lb & 7) * 128;

    const int tid = threadIdx.x;
    const int lane = tid & 63, wv = tid >> 6;
    const int wr = wv >> 1, wc = wv & 1;
    const int m = lane & 15, g = lane >> 4;

    f32x4 acc[4][4];
#pragma unroll
    for (int i2 = 0; i2 < 4; ++i2)
#pragma unroll
        for (int j = 0; j < 4; ++j) acc[i2][j] = zero4();

    for (int k0 = 0; k0 < 1024; k0 += 64) {
        stage64<128>(A  + (size_t)m0 * 1024 + k0, 1024, As, tid);
        stage64<128>(Bt + (size_t)n0 * 1024 + k0, 1024, Bs, tid);
        __syncthreads();
#pragma unroll
        for (int kk = 0; kk < 64; kk += 32) {
            bf16x8 af[4], bfr[4];
#pragma unroll
            for (int mi = 0; mi < 4; ++mi) {
                int row = wr * 64 + mi * 16 + m;
                af[mi] = *(const bf16x8*)&As[(row * 64 + kk + g * 8) ^ ((row & 7) << 3)];
            }
#pragma unroll
            for (int ni = 0; ni < 4; ++ni) {
                int row = wc * 64 + ni * 16 + m;
                bfr[ni] = *(const bf16x8*)&Bs[(row * 64 + kk + g * 8) ^ ((row & 7) << 3)];
            }
#pragma unroll
            for (int mi = 0; mi < 4; ++mi)
#pragma unroll
                for (int ni = 0; ni < 4; ++ni)
                    acc[mi][ni] = __builtin_amdgcn_mfma_f32_16x16x32_bf16(
                        af[mi], bfr[ni], acc[mi][ni], 0, 0, 0);
        }
        __syncthreads();
    }

    if (task < 2) {
        // normal epilogue: C[row][HID] bf16
#pragma unroll
        for (int mi = 0; mi < 4; ++mi)
#pragma unroll
            for (int r = 0; r < 4; ++r) {
                int row = m0 + wr * 64 + mi * 16 + g * 4 + r;
#pragma unroll
                for (int ni = 0; ni < 4; ++ni) {
                    int col = n0 + wc * 64 + ni * 16 + m;
                    C[(size_t)row * HID + col] = f2bf(acc[mi][ni][r]);
                }
            }
    } else {
        // transposed epilogue -> hvT[b*HID + ch][KLEN]
        // T[ch][kv] with kv-granule swizzle: granule gg of col ch stored at
        // slot gg ^ (ch&7); within-granule offset = kv&7.
        u16* T = (u16*)lds;                  // 128(ch) x 128(kv) bf16 = 32KB
        __syncthreads();
#pragma unroll
        for (int mi = 0; mi < 4; ++mi)
#pragma unroll
            for (int ni = 0; ni < 4; ++ni)
#pragma unroll
                for (int r = 0; r < 4; ++r) {
                    int row = wr * 64 + mi * 16 + g * 4 + r;   // kv-local
                    int col = wc * 64 + ni * 16 + m;           // ch-local
                    T[col * 128 + ((((row >> 3) ^ (col & 7)) << 3) + (row & 7))] =
                        f2bf(acc[mi][ni][r]);
                }
        __syncthreads();
        const int b = m0 >> 11, kv0 = m0 & 2047;
        // 128 rows x 16 granules = 2048 chunks of 16B
#pragma unroll
        for (int it = 0; it < 8; ++it) {
            int idx = it * 256 + tid;
            int orow = idx >> 4, og = idx & 15;
            u32x4 x = *(const u32x4*)&T[orow * 128 + ((og ^ (orow & 7)) << 3)];
            *(u32x4*)&hvT[(size_t)(b * HID + n0 + orow) * KLEN + kv0 + og * 8] = x;
        }
    }
}

// ---------------------------------------------------------------------------
// Fused sigmoid-attention, kv-split = 2.
// Grid (16 qt, 16 h, 4 = b*2+split), 4 waves; wave owns 16 q rows x 1024 kv.
// K and V^T tiles staged via global_load_lds (pre-swizzled source).
// Output: f32 partial O into O0/O1.
// ---------------------------------------------------------------------------
__global__ __launch_bounds__(256) void attn_kernel(
    const u16* __restrict__ hq, const u16* __restrict__ hk,
    const u16* __restrict__ hvT, const int* __restrict__ amask,
    float* __restrict__ O0, float* __restrict__ O1)
{
    __shared__ u32x4 KsBuf[512];             // 8KB
    __shared__ u32x4 VtBuf[512];             // 8KB
    __shared__ __align__(16) float Ml[64];
    __shared__ __align__(16) u16 Pw[4][16 * 40];  // padded stride 40
    u16* Ks = (u16*)KsBuf;
    u16* Vt = (u16*)VtBuf;

    const int tid = threadIdx.x;
    const int lane = tid & 63, wv = tid >> 6;
    const int m = lane & 15, g = lane >> 4;
    const int qt = blockIdx.x, h = blockIdx.y;
    const int b = blockIdx.z >> 1, sp = blockIdx.z & 1;
    const int qrow0 = qt * 64 + wv * 16;
    float* Op = sp ? O1 : O0;
    u16* P = Pw[wv];

    const u16* qp = &hq[(size_t)(b * QLEN + qrow0 + m) * HID + h * HD + g * 8];
    bf16x8 qf0 = *(const bf16x8*)qp;
    bf16x8 qf1 = *(const bf16x8*)(qp + 32);

    const u16* kbase = hk + (size_t)(b * KLEN + sp * 1024) * HID + h * HD;
    const u16* vbase = hvT + (size_t)(b * HID + h * HD) * KLEN + sp * 1024;
    const int* mbase = amask + b * KLEN + sp * 1024;

    f32x4 o[4];
#pragma unroll
    for (int i = 0; i < 4; ++i) o[i] = zero4();

    for (int kv0 = 0; kv0 < 1024; kv0 += 64) {
        stage64<64>(kbase + (size_t)kv0 * HID, HID, Ks, tid);
        stage64<64>(vbase + kv0, KLEN, Vt, tid);
        if (tid < 64) Ml[tid] = (mbase[kv0 + tid] != 0) ? 1.0f : 0.0f;
        __syncthreads();

#pragma unroll
        for (int sub = 0; sub < 2; ++sub) {
#pragma unroll
            for (int t = 0; t < 2; ++t) {
                int kvr = sub * 32 + t * 16 + m;
                bf16x8 ak0 = *(const bf16x8*)&Ks[(kvr * 64 + g * 8) ^ ((kvr & 7) << 3)];
                bf16x8 ak1 = *(const bf16x8*)&Ks[(kvr * 64 + 32 + g * 8) ^ ((kvr & 7) << 3)];
                f32x4 s = zero4();
                s = __builtin_amdgcn_mfma_f32_16x16x32_bf16(ak0, qf0, s, 0, 0, 0);
                s = __builtin_amdgcn_mfma_f32_16x16x32_bf16(ak1, qf1, s, 0, 0, 0);
                // lane holds S^T[kv = sub*32 + t*16 + 4g + r][q = m]
                f32x4 mk = *(const f32x4*)&Ml[sub * 32 + t * 16 + 4 * g];
                float p0 = mk[0] * sigm(s[0] * SCALE);
                float p1 = mk[1] * sigm(s[1] * SCALE);
                float p2 = mk[2] * sigm(s[2] * SCALE);
                float p3 = mk[3] * sigm(s[3] * SCALE);
                u32x2 pp = { pack2bf(p0, p1), pack2bf(p2, p3) };
                *(u32x2*)&P[m * 40 + t * 16 + 4 * g] = pp;    // P[q=m][j-local]
            }
            // same-wave roundtrip: lane reads P[q=m][8g..8g+7]
            bf16x8 pa = *(const bf16x8*)&P[m * 40 + 8 * g];
#pragma unroll
            for (int nt = 0; nt < 4; ++nt) {
                int d = 16 * nt + m;
                bf16x8 vt = *(const bf16x8*)&Vt[(d * 64 + sub * 32 + g * 8) ^ ((d & 7) << 3)];
                o[nt] = __builtin_amdgcn_mfma_f32_16x16x32_bf16(pa, vt, o[nt], 0, 0, 0);
            }
        }
        __syncthreads();
    }
    // lane reg r holds O[q = 4g+r][d = 16nt+m]
#pragma unroll
    for (int nt = 0; nt < 4; ++nt)
#pragma unroll
        for (int r = 0; r < 4; ++r)
            Op[(size_t)(b * QLEN + qrow0 + 4 * g + r) * HID + h * HD + 16 * nt + m] =
                o[nt][r];
}

// ---------------------------------------------------------------------------
// Output projection: out = (O0+O1) @ Wo. 64x128 tile, grid (32,8) = 256 blocks.
// Same-A-panel blocks (same blockIdx.x) share an XCD under round-robin.
// ---------------------------------------------------------------------------
__global__ __launch_bounds__(256) void oproj_kernel(
    const float* __restrict__ O0, const float* __restrict__ O1,
    const u16* __restrict__ Bt, float* __restrict__ out)
{
    __shared__ u32x4 lds[1536];              // As 8KB | Bs 16KB
    u16* As = (u16*)lds;
    u16* Bs = (u16*)(lds + 512);

    const int tid = threadIdx.x;
    const int lane = tid & 63, wv = tid >> 6;
    const int wr = wv >> 1, wc = wv & 1;
    const int m = lane & 15, g = lane >> 4;
    const int m0 = blockIdx.x * 64, n0 = blockIdx.y * 128;

    f32x4 acc[2][4];
#pragma unroll
    for (int i = 0; i < 2; ++i)
#pragma unroll
        for (int j = 0; j < 4; ++j) acc[i][j] = zero4();

    for (int k0 = 0; k0 < 1024; k0 += 64) {
        stage64<128>(Bt + (size_t)n0 * 1024 + k0, 1024, Bs, tid);
        // A: 64 rows x 8 granules = 512 chunks, reg-staged f32 sum -> bf16
#pragma unroll
        for (int c = 0; c < 2; ++c) {
            int idx = c * 256 + tid;
            int row = idx >> 3, cg = idx & 7;
            size_t off = (size_t)(m0 + row) * 1024 + k0 + cg * 8;
            float4 a0 = *(const float4*)&O0[off];
            float4 a1 = *(const float4*)&O0[off + 4];
            float4 b0 = *(const float4*)&O1[off];
            float4 b1 = *(const float4*)&O1[off + 4];
            u32x4 w;
            w[0] = pack2bf(a0.x + b0.x, a0.y + b0.y);
            w[1] = pack2bf(a0.z + b0.z, a0.w + b0.w);
            w[2] = pack2bf(a1.x + b1.x, a1.y + b1.y);
            w[3] = pack2bf(a1.z + b1.z, a1.w + b1.w);
            *(u32x4*)&As[(row * 64 + cg * 8) ^ ((row & 7) << 3)] = w;
        }
        __syncthreads();
#pragma unroll
        for (int kk = 0; kk < 64; kk += 32) {
            bf16x8 af[2], bfr[4];
#pragma unroll
            for (int mi = 0; mi < 2; ++mi) {
                int row = wr * 32 + mi * 16 + m;
                af[mi] = *(const bf16x8*)&As[(row * 64 + kk + g * 8) ^ ((row & 7) << 3)];
            }
#pragma unroll
            for (int ni = 0; ni < 4; ++ni) {
                int row = wc * 64 + ni * 16 + m;
                bfr[ni] = *(const bf16x8*)&Bs[(row * 64 + kk + g * 8) ^ ((row & 7) << 3)];
            }
#pragma unroll
            for (int mi = 0; mi < 2; ++mi)
#pragma unroll
                for (int ni = 0; ni < 4; ++ni)
                    acc[mi][ni] = __builtin_amdgcn_mfma_f32_16x16x32_bf16(
                        af[mi], bfr[ni], acc[mi][ni], 0, 0, 0);
        }
        __syncthreads();
    }
#pragma unroll
    for (int mi = 0; mi < 2; ++mi)
#pragma unroll
        for (int r = 0; r < 4; ++r) {
            int row = m0 + wr * 32 + mi * 16 + g * 4 + r;
#pragma unroll
            for (int ni = 0; ni < 4; ++ni) {
                int col = n0 + wc * 64 + ni * 16 + m;
                out[(size_t)row * HID + col] = acc[mi][ni][r];
            }
        }
}

// ---------------------------------------------------------------------------
extern "C" void kernel_launch(void* const* d_in, const int* in_sizes, int n_in,
                              void* d_out, int out_size, void* d_ws, size_t ws_size,
                              hipStream_t stream)
{
    const float* query = (const float*)d_in[0];
    const float* key   = (const float*)d_in[1];
    const float* value = (const float*)d_in[2];
    const int*   amask = (const int*)d_in[3];
    const float* Wq    = (const float*)d_in[4];
    const float* Wk    = (const float*)d_in[5];
    const float* Wv    = (const float*)d_in[6];
    const float* Wo    = (const float*)d_in[7];

    char* ws = (char*)d_ws;
    u16* wtq = (u16*)(ws + (0ull  << 20));   // 2MB
    u16* wtk = (u16*)(ws + (2ull  << 20));   // 2MB
    u16* wtv = (u16*)(ws + (4ull  << 20));   // 2MB
    u16* wto = (u16*)(ws + (6ull  << 20));   // 2MB
    u16* hq  = (u16*)(ws + (8ull  << 20));   // 4MB  bf16 [2048][1024]
    u16* hk  = (u16*)(ws + (12ull << 20));   // 8MB  bf16 [4096][1024]
    u16* hvT = (u16*)(ws + (20ull << 20));   // 8MB  bf16 [2048][2048] (b*HID+ch, kv)
    u16* qbf = (u16*)(ws + (28ull << 20));   // 4MB  bf16 [2048][1024]
    u16* kbf = (u16*)(ws + (32ull << 20));   // 8MB  bf16 [4096][1024]
    u16* vbf = (u16*)(ws + (40ull << 20));   // 8MB  bf16 [4096][1024]
    // O0/O1 alias qbf/kbf/vbf (dead after qkv_gemm)
    float* O0 = (float*)(ws + (28ull << 20)); // 8MB f32 [2048][1024]
    float* O1 = (float*)(ws + (36ull << 20)); // 8MB

    a2bf_kernel<<<dim3(5120), 256, 0, stream>>>(query, key, value, qbf, kbf, vbf);
    wtrans_kernel<<<dim3(16, 16, 4), 256, 0, stream>>>(Wq, Wk, Wv, Wo, wtq, wtk, wtv, wto);
    qkv_gemm_kernel<<<dim3(640), 256, 0, stream>>>(qbf, kbf, vbf, wtq, wtk, wtv, hq, hk, hvT);
    attn_kernel<<<dim3(16, 16, 4), 256, 0, stream>>>(hq, hk, hvT, amask, O0, O1);
    oproj_kernel<<<dim3(32, 8), 256, 0, stream>>>(O0, O1, wto, (float*)d_out);
}

// Round 9
// 201.993 us; speedup vs baseline: 1.3791x; 1.1072x over previous
//
#include <hip/hip_runtime.h>
#include <hip/hip_bf16.h>

#define BSZ 2
#define QLEN 1024
#define KLEN 2048
#define HID 1024
#define NH 16
#define HD 64
#define SCALE 0.125f

using f32x4 = __attribute__((ext_vector_type(4))) float;
using bf16x8 = __attribute__((ext_vector_type(8))) short;   // 8 bf16 (4 VGPRs)
using u32x4 = __attribute__((ext_vector_type(4))) unsigned int;
using u32x2 = __attribute__((ext_vector_type(2))) unsigned int;
typedef unsigned short u16;

// packed f32x2 -> bf16x2 (RNE), single instruction
__device__ __forceinline__ unsigned int cvtpk(float a, float b) {
    unsigned int r;
    asm("v_cvt_pk_bf16_f32 %0, %1, %2" : "=v"(r) : "v"(a), "v"(b));
    return r;
}
__device__ __forceinline__ unsigned int pack2bf(float a, float b) { return cvtpk(a, b); }
__device__ __forceinline__ u16 f2bf(float x) { return (u16)cvtpk(x, x); }
__device__ __forceinline__ f32x4 zero4() {
    f32x4 z = {0.0f, 0.0f, 0.0f, 0.0f};
    return z;
}

// async global->LDS, 16B per lane
__device__ __forceinline__ void gl16(const void* g, void* l) {
    __builtin_amdgcn_global_load_lds(
        (const __attribute__((address_space(1))) void*)g,
        (__attribute__((address_space(3))) void*)l, 16, 0, 0);
}

// Stage a [ROWS][64] bf16 tile (row stride gstride elems) into linear LDS via
// global_load_lds, with source pre-swizzle so LDS slot s of row r holds global
// granule s ^ (r&7). Read back granule gg at element ((r*64+gg*8) ^ ((r&7)<<3)).
template<int ROWS>
__device__ __forceinline__ void stage64(const u16* __restrict__ g, size_t gstride,
                                        u16* lds, int tid) {
    const int lane = tid & 63, wv = tid >> 6;
    constexpr int RPW = ROWS / 4;        // rows per wave
#pragma unroll
    for (int c = 0; c < RPW / 8; ++c) {
        int row = wv * RPW + c * 8 + (lane >> 3);
        int cg = (lane & 7) ^ (row & 7);
        gl16(g + (size_t)row * gstride + cg * 8, lds + (size_t)(wv * RPW + c * 8) * 64);
    }
}

// ---------------------------------------------------------------------------
// f32 -> bf16 conversion of query/key/value activations (one-shot).
// ---------------------------------------------------------------------------
__global__ __launch_bounds__(256) void a2bf_kernel(
    const float* __restrict__ Aq, const float* __restrict__ Ak,
    const float* __restrict__ Av,
    u16* __restrict__ qbf, u16* __restrict__ kbf, u16* __restrict__ vbf)
{
    const int bid = blockIdx.x;
    const float* src; u16* dst; size_t base;
    if (bid < 1024)      { src = Aq; dst = qbf; base = (size_t)bid * 2048; }
    else if (bid < 3072) { src = Ak; dst = kbf; base = (size_t)(bid - 1024) * 2048; }
    else                 { src = Av; dst = vbf; base = (size_t)(bid - 3072) * 2048; }
    size_t e = base + (size_t)threadIdx.x * 8;
    float4 x0 = *(const float4*)&src[e];
    float4 x1 = *(const float4*)&src[e + 4];
    u32x4 w;
    w[0] = pack2bf(x0.x, x0.y); w[1] = pack2bf(x0.z, x0.w);
    w[2] = pack2bf(x1.x, x1.y); w[3] = pack2bf(x1.z, x1.w);
    *(u32x4*)&dst[e] = w;
}

// ---------------------------------------------------------------------------
// Weight transpose + f32->bf16: W[K=1024][N=1024] f32  ->  Wt[N][K] bf16
// ---------------------------------------------------------------------------
__global__ __launch_bounds__(256) void wtrans_kernel(
    const float* __restrict__ W0, const float* __restrict__ W1,
    const float* __restrict__ W2, const float* __restrict__ W3,
    u16* __restrict__ T0, u16* __restrict__ T1,
    u16* __restrict__ T2, u16* __restrict__ T3)
{
    const float* W = blockIdx.z == 0 ? W0 : blockIdx.z == 1 ? W1 : blockIdx.z == 2 ? W2 : W3;
    u16* T = blockIdx.z == 0 ? T0 : blockIdx.z == 1 ? T1 : blockIdx.z == 2 ? T2 : T3;
    __shared__ float tile[64][65];
    const int tid = threadIdx.x;
    const int r0 = blockIdx.x * 64;   // K dim
    const int c0 = blockIdx.y * 64;   // N dim
#pragma unroll
    for (int i = 0; i < 4; ++i) {
        int ch = i * 256 + tid;
        int row = ch >> 4, cg = ch & 15;
        float4 x = *(const float4*)&W[(size_t)(r0 + row) * 1024 + c0 + cg * 4];
        tile[row][cg * 4 + 0] = x.x;
        tile[row][cg * 4 + 1] = x.y;
        tile[row][cg * 4 + 2] = x.z;
        tile[row][cg * 4 + 3] = x.w;
    }
    __syncthreads();
#pragma unroll
    for (int i = 0; i < 2; ++i) {
        int ch = i * 256 + tid;
        int orow = ch >> 3, ocg = ch & 7;
        u32x4 o;
#pragma unroll
        for (int j = 0; j < 4; ++j)
            o[j] = pack2bf(tile[ocg * 8 + 2 * j][orow], tile[ocg * 8 + 2 * j + 1][orow]);
        *(u32x4*)&T[(size_t)(c0 + orow) * 1024 + r0 + ocg * 8] = o;
    }
}

// ---------------------------------------------------------------------------
// Fused QKV projection GEMM, all-bf16, both operands via global_load_lds.
// bid 0..127: Q (M=2048), 128..383: K (M=4096), 384..639: V (M=4096).
// 128x128 tile, BK=64, 4 waves. XCD-swizzled block order.
// V task writes TRANSPOSED output hvT[b*HID + ch][KLEN] via LDS transpose.
// ---------------------------------------------------------------------------
__global__ __launch_bounds__(256) void qkv_gemm_kernel(
    const u16* __restrict__ Aq, const u16* __restrict__ Ak, const u16* __restrict__ Av,
    const u16* __restrict__ Bq, const u16* __restrict__ Bk, const u16* __restrict__ Bv,
    u16* __restrict__ hq, u16* __restrict__ hk, u16* __restrict__ hvT)
{
    __shared__ u32x4 lds[2048];              // 32KB: As 16KB | Bs 16KB
    u16* As = (u16*)lds;
    u16* Bs = (u16*)(lds + 1024);

    const int i = blockIdx.x;                // 640 blocks
    const int bid = (i & 7) * 80 + (i >> 3); // XCD-contiguous chunks of 80
    const u16* A; const u16* Bt; u16* C; int lb, task;
    if (bid < 128)      { task = 0; A = Aq; Bt = Bq; C = hq; lb = bid; }
    else if (bid < 384) { task = 1; A = Ak; Bt = Bk; C = hk; lb = bid - 128; }
    else                { task = 2; A = Av; Bt = Bv; C = nullptr; lb = bid - 384; }
    const int m0 = (lb >> 3) * 128, n0 = (lb & 7) * 128;

    const int tid = threadIdx.x;
    const int lane = tid & 63, wv = tid >> 6;
    const int wr = wv >> 1, wc = wv & 1;
    const int m = lane & 15, g = lane >> 4;

    f32x4 acc[4][4];
#pragma unroll
    for (int i2 = 0; i2 < 4; ++i2)
#pragma unroll
        for (int j = 0; j < 4; ++j) acc[i2][j] = zero4();

    for (int k0 = 0; k0 < 1024; k0 += 64) {
        stage64<128>(A  + (size_t)m0 * 1024 + k0, 1024, As, tid);
        stage64<128>(Bt + (size_t)n0 * 1024 + k0, 1024, Bs, tid);
        __syncthreads();
#pragma unroll
        for (int kk = 0; kk < 64; kk += 32) {
            bf16x8 af[4], bfr[4];
#pragma unroll
            for (int mi = 0; mi < 4; ++mi) {
                int row = wr * 64 + mi * 16 + m;
                af[mi] = *(const bf16x8*)&As[(row * 64 + kk + g * 8) ^ ((row & 7) << 3)];
            }
#pragma unroll
            for (int ni = 0; ni < 4; ++ni) {
                int row = wc * 64 + ni * 16 + m;
                bfr[ni] = *(const bf16x8*)&Bs[(row * 64 + kk + g * 8) ^ ((row & 7) << 3)];
            }
#pragma unroll
            for (int mi = 0; mi < 4; ++mi)
#pragma unroll
                for (int ni = 0; ni < 4; ++ni)
                    acc[mi][ni] = __builtin_amdgcn_mfma_f32_16x16x32_bf16(
                        af[mi], bfr[ni], acc[mi][ni], 0, 0, 0);
        }
        __syncthreads();
    }

    if (task < 2) {
#pragma unroll
        for (int mi = 0; mi < 4; ++mi)
#pragma unroll
            for (int r = 0; r < 4; ++r) {
                int row = m0 + wr * 64 + mi * 16 + g * 4 + r;
#pragma unroll
                for (int ni = 0; ni < 4; ++ni) {
                    int col = n0 + wc * 64 + ni * 16 + m;
                    C[(size_t)row * HID + col] = f2bf(acc[mi][ni][r]);
                }
            }
    } else {
        // transposed epilogue -> hvT[b*HID + ch][KLEN]
        u16* T = (u16*)lds;                  // 128(ch) x 128(kv) bf16 = 32KB
        __syncthreads();
#pragma unroll
        for (int mi = 0; mi < 4; ++mi)
#pragma unroll
            for (int ni = 0; ni < 4; ++ni)
#pragma unroll
                for (int r = 0; r < 4; ++r) {
                    int row = wr * 64 + mi * 16 + g * 4 + r;   // kv-local
                    int col = wc * 64 + ni * 16 + m;           // ch-local
                    T[col * 128 + ((((row >> 3) ^ (col & 7)) << 3) + (row & 7))] =
                        f2bf(acc[mi][ni][r]);
                }
        __syncthreads();
        const int b = m0 >> 11, kv0 = m0 & 2047;
#pragma unroll
        for (int it = 0; it < 8; ++it) {
            int idx = it * 256 + tid;
            int orow = idx >> 4, og = idx & 15;
            u32x4 x = *(const u32x4*)&T[orow * 128 + ((og ^ (orow & 7)) << 3)];
            *(u32x4*)&hvT[(size_t)(b * HID + n0 + orow) * KLEN + kv0 + og * 8] = x;
        }
    }
}

// ---------------------------------------------------------------------------
// Fused sigmoid-attention, kv-split = 2, double-buffered K/V staging.
// 1024 blocks (XCD-swizzled), 4 waves; wave owns 16 q rows x 1024 kv.
// ---------------------------------------------------------------------------
__device__ __forceinline__ void attn_tile(
    const u16* __restrict__ Ks, const u16* __restrict__ Vt,
    const float* __restrict__ Mlc, u16* __restrict__ P,
    bf16x8 qf0, bf16x8 qf1, int m, int g, f32x4* o)
{
#pragma unroll
    for (int sub = 0; sub < 2; ++sub) {
#pragma unroll
        for (int t = 0; t < 2; ++t) {
            int kvr = sub * 32 + t * 16 + m;
            bf16x8 ak0 = *(const bf16x8*)&Ks[(kvr * 64 + g * 8) ^ ((kvr & 7) << 3)];
            bf16x8 ak1 = *(const bf16x8*)&Ks[(kvr * 64 + 32 + g * 8) ^ ((kvr & 7) << 3)];
            f32x4 s = zero4();
            s = __builtin_amdgcn_mfma_f32_16x16x32_bf16(ak0, qf0, s, 0, 0, 0);
            s = __builtin_amdgcn_mfma_f32_16x16x32_bf16(ak1, qf1, s, 0, 0, 0);
            // lane holds S^T[kv = sub*32 + t*16 + 4g + r][q = m]
            f32x4 mk = *(const f32x4*)&Mlc[sub * 32 + t * 16 + 4 * g];
            float p0 = mk[0] * __builtin_amdgcn_rcpf(1.0f + __expf(s[0] * -SCALE));
            float p1 = mk[1] * __builtin_amdgcn_rcpf(1.0f + __expf(s[1] * -SCALE));
            float p2 = mk[2] * __builtin_amdgcn_rcpf(1.0f + __expf(s[2] * -SCALE));
            float p3 = mk[3] * __builtin_amdgcn_rcpf(1.0f + __expf(s[3] * -SCALE));
            u32x2 pp = { cvtpk(p0, p1), cvtpk(p2, p3) };
            *(u32x2*)&P[m * 40 + t * 16 + 4 * g] = pp;    // P[q=m][j-local]
        }
        // same-wave roundtrip: lane reads P[q=m][8g..8g+7]
        bf16x8 pa = *(const bf16x8*)&P[m * 40 + 8 * g];
#pragma unroll
        for (int nt = 0; nt < 4; ++nt) {
            int d = 16 * nt + m;
            bf16x8 vt = *(const bf16x8*)&Vt[(d * 64 + sub * 32 + g * 8) ^ ((d & 7) << 3)];
            o[nt] = __builtin_amdgcn_mfma_f32_16x16x32_bf16(pa, vt, o[nt], 0, 0, 0);
        }
    }
}

__global__ __launch_bounds__(256) void attn_kernel(
    const u16* __restrict__ hq, const u16* __restrict__ hk,
    const u16* __restrict__ hvT, const int* __restrict__ amask,
    float* __restrict__ O0, float* __restrict__ O1)
{
    __shared__ u32x4 KsBuf[2][512];          // 2 x 8KB
    __shared__ u32x4 VtBuf[2][512];          // 2 x 8KB
    __shared__ __align__(16) float Ml[2][64];
    __shared__ __align__(16) u16 Pw[4][16 * 40];  // padded stride 40

    const int tid = threadIdx.x;
    const int lane = tid & 63, wv = tid >> 6;
    const int m = lane & 15, g = lane >> 4;
    const int li = blockIdx.x;               // 1024 blocks
    const int bid = (li & 7) * 128 + (li >> 3); // XCD-contiguous chunks of 128
    const int qt = bid & 15, h = (bid >> 4) & 15, z = bid >> 8;
    const int b = z >> 1, sp = z & 1;
    const int qrow0 = qt * 64 + wv * 16;
    float* Op = sp ? O1 : O0;
    u16* P = Pw[wv];
    u16* Ks0 = (u16*)KsBuf[0]; u16* Ks1 = (u16*)KsBuf[1];
    u16* Vt0 = (u16*)VtBuf[0]; u16* Vt1 = (u16*)VtBuf[1];

    const u16* qp = &hq[(size_t)(b * QLEN + qrow0 + m) * HID + h * HD + g * 8];
    bf16x8 qf0 = *(const bf16x8*)qp;
    bf16x8 qf1 = *(const bf16x8*)(qp + 32);

    const u16* kbase = hk + (size_t)(b * KLEN + sp * 1024) * HID + h * HD;
    const u16* vbase = hvT + (size_t)(b * HID + h * HD) * KLEN + sp * 1024;
    const int* mbase = amask + b * KLEN + sp * 1024;

    f32x4 o[4];
#pragma unroll
    for (int i = 0; i < 4; ++i) o[i] = zero4();

    // prologue: stage tile 0 into buf0
    stage64<64>(kbase, HID, Ks0, tid);
    stage64<64>(vbase, KLEN, Vt0, tid);
    if (tid < 64) Ml[0][tid] = (mbase[tid] != 0) ? 1.0f : 0.0f;
    __syncthreads();

#pragma unroll 1
    for (int it = 0; it < 16; it += 2) {
        // prefetch tile it+1 -> buf1, compute tile it from buf0
        stage64<64>(kbase + (size_t)(it + 1) * 64 * HID, HID, Ks1, tid);
        stage64<64>(vbase + (it + 1) * 64, KLEN, Vt1, tid);
        if (tid < 64) Ml[1][tid] = (mbase[(it + 1) * 64 + tid] != 0) ? 1.0f : 0.0f;
        attn_tile(Ks0, Vt0, Ml[0], P, qf0, qf1, m, g, o);
        __syncthreads();
        // prefetch tile it+2 -> buf0, compute tile it+1 from buf1
        if (it + 2 < 16) {
            stage64<64>(kbase + (size_t)(it + 2) * 64 * HID, HID, Ks0, tid);
            stage64<64>(vbase + (it + 2) * 64, KLEN, Vt0, tid);
            if (tid < 64) Ml[0][tid] = (mbase[(it + 2) * 64 + tid] != 0) ? 1.0f : 0.0f;
        }
        attn_tile(Ks1, Vt1, Ml[1], P, qf0, qf1, m, g, o);
        __syncthreads();
    }
    // lane reg r holds O[q = 4g+r][d = 16nt+m]
#pragma unroll
    for (int nt = 0; nt < 4; ++nt)
#pragma unroll
        for (int r = 0; r < 4; ++r)
            Op[(size_t)(b * QLEN + qrow0 + 4 * g + r) * HID + h * HD + 16 * nt + m] =
                o[nt][r];
}

// ---------------------------------------------------------------------------
// Output projection: out = (O0+O1) @ Wo. 64x128 tile, grid (32,8) = 256 blocks.
// ---------------------------------------------------------------------------
__global__ __launch_bounds__(256) void oproj_kernel(
    const float* __restrict__ O0, const float* __restrict__ O1,
    const u16* __restrict__ Bt, float* __restrict__ out)
{
    __shared__ u32x4 lds[1536];              // As 8KB | Bs 16KB
    u16* As = (u16*)lds;
    u16* Bs = (u16*)(lds + 512);

    const int tid = threadIdx.x;
    const int lane = tid & 63, wv = tid >> 6;
    const int wr = wv >> 1, wc = wv & 1;
    const int m = lane & 15, g = lane >> 4;
    const int m0 = blockIdx.x * 64, n0 = blockIdx.y * 128;

    f32x4 acc[2][4];
#pragma unroll
    for (int i = 0; i < 2; ++i)
#pragma unroll
        for (int j = 0; j < 4; ++j) acc[i][j] = zero4();

    for (int k0 = 0; k0 < 1024; k0 += 64) {
        stage64<128>(Bt + (size_t)n0 * 1024 + k0, 1024, Bs, tid);
        // A: 64 rows x 8 granules = 512 chunks, reg-staged f32 sum -> bf16
#pragma unroll
        for (int c = 0; c < 2; ++c) {
            int idx = c * 256 + tid;
            int row = idx >> 3, cg = idx & 7;
            size_t off = (size_t)(m0 + row) * 1024 + k0 + cg * 8;
            float4 a0 = *(const float4*)&O0[off];
            float4 a1 = *(const float4*)&O0[off + 4];
            float4 b0 = *(const float4*)&O1[off];
            float4 b1 = *(const float4*)&O1[off + 4];
            u32x4 w;
            w[0] = pack2bf(a0.x + b0.x, a0.y + b0.y);
            w[1] = pack2bf(a0.z + b0.z, a0.w + b0.w);
            w[2] = pack2bf(a1.x + b1.x, a1.y + b1.y);
            w[3] = pack2bf(a1.z + b1.z, a1.w + b1.w);
            *(u32x4*)&As[(row * 64 + cg * 8) ^ ((row & 7) << 3)] = w;
        }
        __syncthreads();
#pragma unroll
        for (int kk = 0; kk < 64; kk += 32) {
            bf16x8 af[2], bfr[4];
#pragma unroll
            for (int mi = 0; mi < 2; ++mi) {
                int row = wr * 32 + mi * 16 + m;
                af[mi] = *(const bf16x8*)&As[(row * 64 + kk + g * 8) ^ ((row & 7) << 3)];
            }
#pragma unroll
            for (int ni = 0; ni < 4; ++ni) {
                int row = wc * 64 + ni * 16 + m;
                bfr[ni] = *(const bf16x8*)&Bs[(row * 64 + kk + g * 8) ^ ((row & 7) << 3)];
            }
#pragma unroll
            for (int mi = 0; mi < 2; ++mi)
#pragma unroll
                for (int ni = 0; ni < 4; ++ni)
                    acc[mi][ni] = __builtin_amdgcn_mfma_f32_16x16x32_bf16(
                        af[mi], bfr[ni], acc[mi][ni], 0, 0, 0);
        }
        __syncthreads();
    }
#pragma unroll
    for (int mi = 0; mi < 2; ++mi)
#pragma unroll
        for (int r = 0; r < 4; ++r) {
            int row = m0 + wr * 32 + mi * 16 + g * 4 + r;
#pragma unroll
            for (int ni = 0; ni < 4; ++ni) {
                int col = n0 + wc * 64 + ni * 16 + m;
                out[(size_t)row * HID + col] = acc[mi][ni][r];
            }
        }
}

// ---------------------------------------------------------------------------
extern "C" void kernel_launch(void* const* d_in, const int* in_sizes, int n_in,
                              void* d_out, int out_size, void* d_ws, size_t ws_size,
                              hipStream_t stream)
{
    const float* query = (const float*)d_in[0];
    const float* key   = (const float*)d_in[1];
    const float* value = (const float*)d_in[2];
    const int*   amask = (const int*)d_in[3];
    const float* Wq    = (const float*)d_in[4];
    const float* Wk    = (const float*)d_in[5];
    const float* Wv    = (const float*)d_in[6];
    const float* Wo    = (const float*)d_in[7];

    char* ws = (char*)d_ws;
    u16* wtq = (u16*)(ws + (0ull  << 20));   // 2MB
    u16* wtk = (u16*)(ws + (2ull  << 20));   // 2MB
    u16* wtv = (u16*)(ws + (4ull  << 20));   // 2MB
    u16* wto = (u16*)(ws + (6ull  << 20));   // 2MB
    u16* hq  = (u16*)(ws + (8ull  << 20));   // 4MB  bf16 [2048][1024]
    u16* hk  = (u16*)(ws + (12ull << 20));   // 8MB  bf16 [4096][1024]
    u16* hvT = (u16*)(ws + (20ull << 20));   // 8MB  bf16 [2048][2048] (b*HID+ch, kv)
    u16* qbf = (u16*)(ws + (28ull << 20));   // 4MB  bf16 [2048][1024]
    u16* kbf = (u16*)(ws + (32ull << 20));   // 8MB  bf16 [4096][1024]
    u16* vbf = (u16*)(ws + (40ull << 20));   // 8MB  bf16 [4096][1024]
    // O0/O1 alias qbf/kbf/vbf (dead after qkv_gemm)
    float* O0 = (float*)(ws + (28ull << 20)); // 8MB f32 [2048][1024]
    float* O1 = (float*)(ws + (36ull << 20)); // 8MB

    a2bf_kernel<<<dim3(5120), 256, 0, stream>>>(query, key, value, qbf, kbf, vbf);
    wtrans_kernel<<<dim3(16, 16, 4), 256, 0, stream>>>(Wq, Wk, Wv, Wo, wtq, wtk, wtv, wto);
    qkv_gemm_kernel<<<dim3(640), 256, 0, stream>>>(qbf, kbf, vbf, wtq, wtk, wtv, hq, hk, hvT);
    attn_kernel<<<dim3(1024), 256, 0, stream>>>(hq, hk, hvT, amask, O0, O1);
    oproj_kernel<<<dim3(32, 8), 256, 0, stream>>>(O0, O1, wto, (float*)d_out);
}

// Round 10
// 190.380 us; speedup vs baseline: 1.4632x; 1.0610x over previous
//
#include <hip/hip_runtime.h>
#include <hip/hip_bf16.h>

#define BSZ 2
#define QLEN 1024
#define KLEN 2048
#define HID 1024
#define NH 16
#define HD 64
#define SCALE 0.125f

using f32x4 = __attribute__((ext_vector_type(4))) float;
using bf16x8 = __attribute__((ext_vector_type(8))) short;   // 8 bf16 (4 VGPRs)
using u32x4 = __attribute__((ext_vector_type(4))) unsigned int;
using u32x2 = __attribute__((ext_vector_type(2))) unsigned int;
typedef unsigned short u16;

// packed f32x2 -> bf16x2 (RNE), single instruction
__device__ __forceinline__ unsigned int cvtpk(float a, float b) {
    unsigned int r;
    asm("v_cvt_pk_bf16_f32 %0, %1, %2" : "=v"(r) : "v"(a), "v"(b));
    return r;
}
__device__ __forceinline__ unsigned int pack2bf(float a, float b) { return cvtpk(a, b); }
__device__ __forceinline__ u16 f2bf(float x) { return (u16)cvtpk(x, x); }
__device__ __forceinline__ f32x4 zero4() {
    f32x4 z = {0.0f, 0.0f, 0.0f, 0.0f};
    return z;
}

// async global->LDS, 16B per lane
__device__ __forceinline__ void gl16(const void* g, void* l) {
    __builtin_amdgcn_global_load_lds(
        (const __attribute__((address_space(1))) void*)g,
        (__attribute__((address_space(3))) void*)l, 16, 0, 0);
}

// Stage a [ROWS][64] bf16 tile (row stride gstride elems) into linear LDS via
// global_load_lds, with source pre-swizzle so LDS slot s of row r holds global
// granule s ^ (r&7). Read back granule gg at element ((r*64+gg*8) ^ ((r&7)<<3)).
template<int ROWS>
__device__ __forceinline__ void stage64(const u16* __restrict__ g, size_t gstride,
                                        u16* lds, int tid) {
    const int lane = tid & 63, wv = tid >> 6;
    constexpr int RPW = ROWS / 4;        // rows per wave
#pragma unroll
    for (int c = 0; c < RPW / 8; ++c) {
        int row = wv * RPW + c * 8 + (lane >> 3);
        int cg = (lane & 7) ^ (row & 7);
        gl16(g + (size_t)row * gstride + cg * 8, lds + (size_t)(wv * RPW + c * 8) * 64);
    }
}

// ---------------------------------------------------------------------------
// Prep: blocks 0..5119 convert q/k/v f32->bf16; 5120..6143 transpose weights.
// ---------------------------------------------------------------------------
__global__ __launch_bounds__(256) void prep_kernel(
    const float* __restrict__ Aq, const float* __restrict__ Ak,
    const float* __restrict__ Av,
    const float* __restrict__ W0, const float* __restrict__ W1,
    const float* __restrict__ W2, const float* __restrict__ W3,
    u16* __restrict__ qbf, u16* __restrict__ kbf, u16* __restrict__ vbf,
    u16* __restrict__ T0, u16* __restrict__ T1,
    u16* __restrict__ T2, u16* __restrict__ T3)
{
    __shared__ float tile[64][65];
    const int bid = blockIdx.x;
    const int tid = threadIdx.x;
    if (bid < 5120) {
        const float* src; u16* dst; size_t base;
        if (bid < 1024)      { src = Aq; dst = qbf; base = (size_t)bid * 2048; }
        else if (bid < 3072) { src = Ak; dst = kbf; base = (size_t)(bid - 1024) * 2048; }
        else                 { src = Av; dst = vbf; base = (size_t)(bid - 3072) * 2048; }
        size_t e = base + (size_t)tid * 8;
        float4 x0 = *(const float4*)&src[e];
        float4 x1 = *(const float4*)&src[e + 4];
        u32x4 w;
        w[0] = pack2bf(x0.x, x0.y); w[1] = pack2bf(x0.z, x0.w);
        w[2] = pack2bf(x1.x, x1.y); w[3] = pack2bf(x1.z, x1.w);
        *(u32x4*)&dst[e] = w;
        return;
    }
    const int lb = bid - 5120;
    const int zi = lb >> 8;
    const float* W = zi == 0 ? W0 : zi == 1 ? W1 : zi == 2 ? W2 : W3;
    u16* T = zi == 0 ? T0 : zi == 1 ? T1 : zi == 2 ? T2 : T3;
    const int r0 = (lb & 15) * 64;           // K dim
    const int c0 = ((lb >> 4) & 15) * 64;    // N dim
#pragma unroll
    for (int i = 0; i < 4; ++i) {
        int ch = i * 256 + tid;
        int row = ch >> 4, cg = ch & 15;
        float4 x = *(const float4*)&W[(size_t)(r0 + row) * 1024 + c0 + cg * 4];
        tile[row][cg * 4 + 0] = x.x;
        tile[row][cg * 4 + 1] = x.y;
        tile[row][cg * 4 + 2] = x.z;
        tile[row][cg * 4 + 3] = x.w;
    }
    __syncthreads();
#pragma unroll
    for (int i = 0; i < 2; ++i) {
        int ch = i * 256 + tid;
        int orow = ch >> 3, ocg = ch & 7;
        u32x4 o;
#pragma unroll
        for (int j = 0; j < 4; ++j)
            o[j] = pack2bf(tile[ocg * 8 + 2 * j][orow], tile[ocg * 8 + 2 * j + 1][orow]);
        *(u32x4*)&T[(size_t)(c0 + orow) * 1024 + r0 + ocg * 8] = o;
    }
}

// ---------------------------------------------------------------------------
// Fused QKV projection GEMM, all-bf16, double-buffered global_load_lds.
// bid 0..127: Q (M=2048), 128..383: K (M=4096), 384..639: V (M=4096).
// 128x128 tile, BK=64, 4 waves, XCD-swizzled block order.
// V task writes TRANSPOSED output hvT[b*HID + ch][KLEN] via LDS transpose.
// ---------------------------------------------------------------------------
__device__ __forceinline__ void gemm_step128(
    const u16* __restrict__ As, const u16* __restrict__ Bs,
    int wr, int wc, int m, int g, f32x4 (*acc)[4])
{
#pragma unroll
    for (int kk = 0; kk < 64; kk += 32) {
        bf16x8 af[4], bfr[4];
#pragma unroll
        for (int mi = 0; mi < 4; ++mi) {
            int row = wr * 64 + mi * 16 + m;
            af[mi] = *(const bf16x8*)&As[(row * 64 + kk + g * 8) ^ ((row & 7) << 3)];
        }
#pragma unroll
        for (int ni = 0; ni < 4; ++ni) {
            int row = wc * 64 + ni * 16 + m;
            bfr[ni] = *(const bf16x8*)&Bs[(row * 64 + kk + g * 8) ^ ((row & 7) << 3)];
        }
#pragma unroll
        for (int mi = 0; mi < 4; ++mi)
#pragma unroll
            for (int ni = 0; ni < 4; ++ni)
                acc[mi][ni] = __builtin_amdgcn_mfma_f32_16x16x32_bf16(
                    af[mi], bfr[ni], acc[mi][ni], 0, 0, 0);
    }
}

__global__ __launch_bounds__(256) void qkv_gemm_kernel(
    const u16* __restrict__ Aq, const u16* __restrict__ Ak, const u16* __restrict__ Av,
    const u16* __restrict__ Bq, const u16* __restrict__ Bk, const u16* __restrict__ Bv,
    u16* __restrict__ hq, u16* __restrict__ hk, u16* __restrict__ hvT)
{
    __shared__ u32x4 lds[4096];              // 64KB: As0|Bs0|As1|Bs1 16KB each
    u16* As0 = (u16*)lds;
    u16* Bs0 = (u16*)(lds + 1024);
    u16* As1 = (u16*)(lds + 2048);
    u16* Bs1 = (u16*)(lds + 3072);

    const int i = blockIdx.x;                // 640 blocks
    const int bid = (i & 7) * 80 + (i >> 3); // XCD-contiguous chunks of 80
    const u16* A; const u16* Bt; u16* C; int lb, task;
    if (bid < 128)      { task = 0; A = Aq; Bt = Bq; C = hq; lb = bid; }
    else if (bid < 384) { task = 1; A = Ak; Bt = Bk; C = hk; lb = bid - 128; }
    else                { task = 2; A = Av; Bt = Bv; C = nullptr; lb = bid - 384; }
    const int m0 = (lb >> 3) * 128, n0 = (lb & 7) * 128;

    const int tid = threadIdx.x;
    const int lane = tid & 63, wv = tid >> 6;
    const int wr = wv >> 1, wc = wv & 1;
    const int m = lane & 15, g = lane >> 4;

    const u16* Ab = A  + (size_t)m0 * 1024;
    const u16* Bb = Bt + (size_t)n0 * 1024;

    f32x4 acc[4][4];
#pragma unroll
    for (int i2 = 0; i2 < 4; ++i2)
#pragma unroll
        for (int j = 0; j < 4; ++j) acc[i2][j] = zero4();

    stage64<128>(Ab, 1024, As0, tid);
    stage64<128>(Bb, 1024, Bs0, tid);
    __syncthreads();
#pragma unroll 1
    for (int k0 = 0; k0 < 1024; k0 += 128) {
        stage64<128>(Ab + k0 + 64, 1024, As1, tid);
        stage64<128>(Bb + k0 + 64, 1024, Bs1, tid);
        gemm_step128(As0, Bs0, wr, wc, m, g, acc);
        __syncthreads();
        if (k0 + 128 < 1024) {
            stage64<128>(Ab + k0 + 128, 1024, As0, tid);
            stage64<128>(Bb + k0 + 128, 1024, Bs0, tid);
        }
        gemm_step128(As1, Bs1, wr, wc, m, g, acc);
        __syncthreads();
    }

    if (task < 2) {
#pragma unroll
        for (int mi = 0; mi < 4; ++mi)
#pragma unroll
            for (int r = 0; r < 4; ++r) {
                int row = m0 + wr * 64 + mi * 16 + g * 4 + r;
#pragma unroll
                for (int ni = 0; ni < 4; ++ni) {
                    int col = n0 + wc * 64 + ni * 16 + m;
                    C[(size_t)row * HID + col] = f2bf(acc[mi][ni][r]);
                }
            }
    } else {
        // transposed epilogue -> hvT[b*HID + ch][KLEN]
        u16* T = (u16*)lds;                  // 128(ch) x 128(kv) bf16 = 32KB
#pragma unroll
        for (int mi = 0; mi < 4; ++mi)
#pragma unroll
            for (int ni = 0; ni < 4; ++ni)
#pragma unroll
                for (int r = 0; r < 4; ++r) {
                    int row = wr * 64 + mi * 16 + g * 4 + r;   // kv-local
                    int col = wc * 64 + ni * 16 + m;           // ch-local
                    T[col * 128 + ((((row >> 3) ^ (col & 7)) << 3) + (row & 7))] =
                        f2bf(acc[mi][ni][r]);
                }
        __syncthreads();
        const int b = m0 >> 11, kv0 = m0 & 2047;
#pragma unroll
        for (int it = 0; it < 8; ++it) {
            int idx = it * 256 + tid;
            int orow = idx >> 4, og = idx & 15;
            u32x4 x = *(const u32x4*)&T[orow * 128 + ((og ^ (orow & 7)) << 3)];
            *(u32x4*)&hvT[(size_t)(b * HID + n0 + orow) * KLEN + kv0 + og * 8] = x;
        }
    }
}

// ---------------------------------------------------------------------------
// Fused sigmoid-attention, NO kv-split, double-buffered K/V staging.
// 512 blocks (XCD-swizzled), 4 waves; wave owns 16 q rows x 2048 kv.
// Output: bf16 O directly to av[2048][1024].
// ---------------------------------------------------------------------------
__device__ __forceinline__ void attn_tile(
    const u16* __restrict__ Ks, const u16* __restrict__ Vt,
    const float* __restrict__ Mlc, u16* __restrict__ P,
    bf16x8 qf0, bf16x8 qf1, int m, int g, f32x4* o)
{
#pragma unroll
    for (int sub = 0; sub < 2; ++sub) {
#pragma unroll
        for (int t = 0; t < 2; ++t) {
            int kvr = sub * 32 + t * 16 + m;
            bf16x8 ak0 = *(const bf16x8*)&Ks[(kvr * 64 + g * 8) ^ ((kvr & 7) << 3)];
            bf16x8 ak1 = *(const bf16x8*)&Ks[(kvr * 64 + 32 + g * 8) ^ ((kvr & 7) << 3)];
            f32x4 s = zero4();
            s = __builtin_amdgcn_mfma_f32_16x16x32_bf16(ak0, qf0, s, 0, 0, 0);
            s = __builtin_amdgcn_mfma_f32_16x16x32_bf16(ak1, qf1, s, 0, 0, 0);
            // lane holds S^T[kv = sub*32 + t*16 + 4g + r][q = m]
            f32x4 mk = *(const f32x4*)&Mlc[sub * 32 + t * 16 + 4 * g];
            float p0 = mk[0] * __builtin_amdgcn_rcpf(1.0f + __expf(s[0] * -SCALE));
            float p1 = mk[1] * __builtin_amdgcn_rcpf(1.0f + __expf(s[1] * -SCALE));
            float p2 = mk[2] * __builtin_amdgcn_rcpf(1.0f + __expf(s[2] * -SCALE));
            float p3 = mk[3] * __builtin_amdgcn_rcpf(1.0f + __expf(s[3] * -SCALE));
            u32x2 pp = { cvtpk(p0, p1), cvtpk(p2, p3) };
            *(u32x2*)&P[m * 40 + t * 16 + 4 * g] = pp;    // P[q=m][j-local]
        }
        // same-wave roundtrip: lane reads P[q=m][8g..8g+7]
        bf16x8 pa = *(const bf16x8*)&P[m * 40 + 8 * g];
#pragma unroll
        for (int nt = 0; nt < 4; ++nt) {
            int d = 16 * nt + m;
            bf16x8 vt = *(const bf16x8*)&Vt[(d * 64 + sub * 32 + g * 8) ^ ((d & 7) << 3)];
            o[nt] = __builtin_amdgcn_mfma_f32_16x16x32_bf16(pa, vt, o[nt], 0, 0, 0);
        }
    }
}

__global__ __launch_bounds__(256) void attn_kernel(
    const u16* __restrict__ hq, const u16* __restrict__ hk,
    const u16* __restrict__ hvT, const int* __restrict__ amask,
    u16* __restrict__ av)
{
    __shared__ u32x4 KsBuf[2][512];          // 2 x 8KB
    __shared__ u32x4 VtBuf[2][512];          // 2 x 8KB
    __shared__ __align__(16) float Ml[2][64];
    __shared__ __align__(16) u16 Pw[4][16 * 40];  // padded stride 40

    const int tid = threadIdx.x;
    const int lane = tid & 63, wv = tid >> 6;
    const int m = lane & 15, g = lane >> 4;
    const int li = blockIdx.x;               // 512 blocks
    const int bid = (li & 7) * 64 + (li >> 3);  // XCD-contiguous chunks of 64
    const int qt = bid & 15, h = (bid >> 4) & 15, b = bid >> 8;
    const int qrow0 = qt * 64 + wv * 16;
    u16* P = Pw[wv];
    u16* Ks0 = (u16*)KsBuf[0]; u16* Ks1 = (u16*)KsBuf[1];
    u16* Vt0 = (u16*)VtBuf[0]; u16* Vt1 = (u16*)VtBuf[1];

    const u16* qp = &hq[(size_t)(b * QLEN + qrow0 + m) * HID + h * HD + g * 8];
    bf16x8 qf0 = *(const bf16x8*)qp;
    bf16x8 qf1 = *(const bf16x8*)(qp + 32);

    const u16* kbase = hk + (size_t)(b * KLEN) * HID + h * HD;
    const u16* vbase = hvT + (size_t)(b * HID + h * HD) * KLEN;
    const int* mbase = amask + b * KLEN;

    f32x4 o[4];
#pragma unroll
    for (int i = 0; i < 4; ++i) o[i] = zero4();

    // prologue: stage tile 0 into buf0
    stage64<64>(kbase, HID, Ks0, tid);
    stage64<64>(vbase, KLEN, Vt0, tid);
    if (tid < 64) Ml[0][tid] = (mbase[tid] != 0) ? 1.0f : 0.0f;
    __syncthreads();

#pragma unroll 1
    for (int it = 0; it < 32; it += 2) {
        stage64<64>(kbase + (size_t)(it + 1) * 64 * HID, HID, Ks1, tid);
        stage64<64>(vbase + (it + 1) * 64, KLEN, Vt1, tid);
        if (tid < 64) Ml[1][tid] = (mbase[(it + 1) * 64 + tid] != 0) ? 1.0f : 0.0f;
        attn_tile(Ks0, Vt0, Ml[0], P, qf0, qf1, m, g, o);
        __syncthreads();
        if (it + 2 < 32) {
            stage64<64>(kbase + (size_t)(it + 2) * 64 * HID, HID, Ks0, tid);
            stage64<64>(vbase + (it + 2) * 64, KLEN, Vt0, tid);
            if (tid < 64) Ml[0][tid] = (mbase[(it + 2) * 64 + tid] != 0) ? 1.0f : 0.0f;
        }
        attn_tile(Ks1, Vt1, Ml[1], P, qf0, qf1, m, g, o);
        __syncthreads();
    }
    // lane reg r holds O[q = 4g+r][d = 16nt+m]
#pragma unroll
    for (int nt = 0; nt < 4; ++nt)
#pragma unroll
        for (int r = 0; r < 4; ++r)
            av[(size_t)(b * QLEN + qrow0 + 4 * g + r) * HID + h * HD + 16 * nt + m] =
                f2bf(o[nt][r]);
}

// ---------------------------------------------------------------------------
// Output projection: out = av @ Wo. av bf16 via global_load_lds, dbuf.
// 64x128 tile, 256 blocks (XCD-swizzled), f32 out.
// ---------------------------------------------------------------------------
__device__ __forceinline__ void oproj_step(
    const u16* __restrict__ As, const u16* __restrict__ Bs,
    int wr, int wc, int m, int g, f32x4 (*acc)[4])
{
#pragma unroll
    for (int kk = 0; kk < 64; kk += 32) {
        bf16x8 af[2], bfr[4];
#pragma unroll
        for (int mi = 0; mi < 2; ++mi) {
            int row = wr * 32 + mi * 16 + m;
            af[mi] = *(const bf16x8*)&As[(row * 64 + kk + g * 8) ^ ((row & 7) << 3)];
        }
#pragma unroll
        for (int ni = 0; ni < 4; ++ni) {
            int row = wc * 64 + ni * 16 + m;
            bfr[ni] = *(const bf16x8*)&Bs[(row * 64 + kk + g * 8) ^ ((row & 7) << 3)];
        }
#pragma unroll
        for (int mi = 0; mi < 2; ++mi)
#pragma unroll
            for (int ni = 0; ni < 4; ++ni)
                acc[mi][ni] = __builtin_amdgcn_mfma_f32_16x16x32_bf16(
                    af[mi], bfr[ni], acc[mi][ni], 0, 0, 0);
    }
}

__global__ __launch_bounds__(256) void oproj_kernel(
    const u16* __restrict__ av, const u16* __restrict__ Bt, float* __restrict__ out)
{
    __shared__ u32x4 lds[3072];              // A0 8K | B0 16K | A1 8K | B1 16K
    u16* As0 = (u16*)lds;
    u16* Bs0 = (u16*)(lds + 512);
    u16* As1 = (u16*)(lds + 1536);
    u16* Bs1 = (u16*)(lds + 2048);

    const int tid = threadIdx.x;
    const int lane = tid & 63, wv = tid >> 6;
    const int wr = wv >> 1, wc = wv & 1;
    const int m = lane & 15, g = lane >> 4;
    const int li = blockIdx.x;               // 256 blocks
    const int bid = (li & 7) * 32 + (li >> 3);
    const int m0 = (bid & 31) * 64, n0 = (bid >> 5) * 128;

    const u16* Ab = av + (size_t)m0 * 1024;
    const u16* Bb = Bt + (size_t)n0 * 1024;

    f32x4 acc[2][4];
#pragma unroll
    for (int i = 0; i < 2; ++i)
#pragma unroll
        for (int j = 0; j < 4; ++j) acc[i][j] = zero4();

    stage64<64>(Ab, 1024, As0, tid);
    stage64<128>(Bb, 1024, Bs0, tid);
    __syncthreads();
#pragma unroll 1
    for (int k0 = 0; k0 < 1024; k0 += 128) {
        stage64<64>(Ab + k0 + 64, 1024, As1, tid);
        stage64<128>(Bb + k0 + 64, 1024, Bs1, tid);
        oproj_step(As0, Bs0, wr, wc, m, g, acc);
        __syncthreads();
        if (k0 + 128 < 1024) {
            stage64<64>(Ab + k0 + 128, 1024, As0, tid);
            stage64<128>(Bb + k0 + 128, 1024, Bs0, tid);
        }
        oproj_step(As1, Bs1, wr, wc, m, g, acc);
        __syncthreads();
    }
#pragma unroll
    for (int mi = 0; mi < 2; ++mi)
#pragma unroll
        for (int r = 0; r < 4; ++r) {
            int row = m0 + wr * 32 + mi * 16 + g * 4 + r;
#pragma unroll
            for (int ni = 0; ni < 4; ++ni) {
                int col = n0 + wc * 64 + ni * 16 + m;
                out[(size_t)row * HID + col] = acc[mi][ni][r];
            }
        }
}

// ---------------------------------------------------------------------------
extern "C" void kernel_launch(void* const* d_in, const int* in_sizes, int n_in,
                              void* d_out, int out_size, void* d_ws, size_t ws_size,
                              hipStream_t stream)
{
    const float* query = (const float*)d_in[0];
    const float* key   = (const float*)d_in[1];
    const float* value = (const float*)d_in[2];
    const int*   amask = (const int*)d_in[3];
    const float* Wq    = (const float*)d_in[4];
    const float* Wk    = (const float*)d_in[5];
    const float* Wv    = (const float*)d_in[6];
    const float* Wo    = (const float*)d_in[7];

    char* ws = (char*)d_ws;
    u16* wtq = (u16*)(ws + (0ull  << 20));   // 2MB
    u16* wtk = (u16*)(ws + (2ull  << 20));   // 2MB
    u16* wtv = (u16*)(ws + (4ull  << 20));   // 2MB
    u16* wto = (u16*)(ws + (6ull  << 20));   // 2MB
    u16* hq  = (u16*)(ws + (8ull  << 20));   // 4MB  bf16 [2048][1024]
    u16* hk  = (u16*)(ws + (12ull << 20));   // 8MB  bf16 [4096][1024]
    u16* hvT = (u16*)(ws + (20ull << 20));   // 8MB  bf16 [2048][2048] (b*HID+ch, kv)
    u16* qbf = (u16*)(ws + (28ull << 20));   // 4MB  bf16 [2048][1024]
    u16* kbf = (u16*)(ws + (32ull << 20));   // 8MB  bf16 [4096][1024]
    u16* vbf = (u16*)(ws + (40ull << 20));   // 8MB  bf16 [4096][1024]
    // av aliases qbf (dead after qkv_gemm)
    u16* av  = (u16*)(ws + (28ull << 20));   // 4MB  bf16 [2048][1024]

    prep_kernel<<<dim3(6144), 256, 0, stream>>>(query, key, value, Wq, Wk, Wv, Wo,
                                                qbf, kbf, vbf, wtq, wtk, wtv, wto);
    qkv_gemm_kernel<<<dim3(640), 256, 0, stream>>>(qbf, kbf, vbf, wtq, wtk, wtv, hq, hk, hvT);
    attn_kernel<<<dim3(512), 256, 0, stream>>>(hq, hk, hvT, amask, av);
    oproj_kernel<<<dim3(256), 256, 0, stream>>>(av, wto, (float*)d_out);
}

// Round 16
// 189.562 us; speedup vs baseline: 1.4695x; 1.0043x over previous
//
#include <hip/hip_runtime.h>
#include <hip/hip_bf16.h>

#define BSZ 2
#define QLEN 1024
#define KLEN 2048
#define HID 1024
#define NH 16
#define HD 64
#define SCALE 0.125f

using f32x4 = __attribute__((ext_vector_type(4))) float;
using bf16x8 = __attribute__((ext_vector_type(8))) short;   // 8 bf16 (4 VGPRs)
using u32x4 = __attribute__((ext_vector_type(4))) unsigned int;
using u32x2 = __attribute__((ext_vector_type(2))) unsigned int;
typedef unsigned short u16;

// packed f32x2 -> bf16x2 (RNE), single instruction
__device__ __forceinline__ unsigned int cvtpk(float a, float b) {
    unsigned int r;
    asm("v_cvt_pk_bf16_f32 %0, %1, %2" : "=v"(r) : "v"(a), "v"(b));
    return r;
}
__device__ __forceinline__ unsigned int pack2bf(float a, float b) { return cvtpk(a, b); }
__device__ __forceinline__ u16 f2bf(float x) { return (u16)cvtpk(x, x); }
__device__ __forceinline__ f32x4 zero4() {
    f32x4 z = {0.0f, 0.0f, 0.0f, 0.0f};
    return z;
}

// async global->LDS, 16B per lane
__device__ __forceinline__ void gl16(const void* g, void* l) {
    __builtin_amdgcn_global_load_lds(
        (const __attribute__((address_space(1))) void*)g,
        (__attribute__((address_space(3))) void*)l, 16, 0, 0);
}

// Stage a [ROWS][64] bf16 tile (row stride gstride elems) into linear LDS via
// global_load_lds, with source pre-swizzle so LDS slot s of row r holds global
// granule s ^ (r&7). Read back granule gg at element ((r*64+gg*8) ^ ((r&7)<<3)).
template<int ROWS>
__device__ __forceinline__ void stage64(const u16* __restrict__ g, size_t gstride,
                                        u16* lds, int tid) {
    const int lane = tid & 63, wv = tid >> 6;
    constexpr int RPW = ROWS / 4;        // rows per wave
#pragma unroll
    for (int c = 0; c < RPW / 8; ++c) {
        int row = wv * RPW + c * 8 + (lane >> 3);
        int cg = (lane & 7) ^ (row & 7);
        gl16(g + (size_t)row * gstride + cg * 8, lds + (size_t)(wv * RPW + c * 8) * 64);
    }
}

// ---------------------------------------------------------------------------
// Prep: blocks 0..5119 convert q/k/v f32->bf16; 5120..6143 transpose weights.
// ---------------------------------------------------------------------------
__global__ __launch_bounds__(256) void prep_kernel(
    const float* __restrict__ Aq, const float* __restrict__ Ak,
    const float* __restrict__ Av,
    const float* __restrict__ W0, const float* __restrict__ W1,
    const float* __restrict__ W2, const float* __restrict__ W3,
    u16* __restrict__ qbf, u16* __restrict__ kbf, u16* __restrict__ vbf,
    u16* __restrict__ T0, u16* __restrict__ T1,
    u16* __restrict__ T2, u16* __restrict__ T3)
{
    __shared__ float tile[64][65];
    const int bid = blockIdx.x;
    const int tid = threadIdx.x;
    if (bid < 5120) {
        const float* src; u16* dst; size_t base;
        if (bid < 1024)      { src = Aq; dst = qbf; base = (size_t)bid * 2048; }
        else if (bid < 3072) { src = Ak; dst = kbf; base = (size_t)(bid - 1024) * 2048; }
        else                 { src = Av; dst = vbf; base = (size_t)(bid - 3072) * 2048; }
        size_t e = base + (size_t)tid * 8;
        float4 x0 = *(const float4*)&src[e];
        float4 x1 = *(const float4*)&src[e + 4];
        u32x4 w;
        w[0] = pack2bf(x0.x, x0.y); w[1] = pack2bf(x0.z, x0.w);
        w[2] = pack2bf(x1.x, x1.y); w[3] = pack2bf(x1.z, x1.w);
        *(u32x4*)&dst[e] = w;
        return;
    }
    const int lb = bid - 5120;
    const int zi = lb >> 8;
    const float* W = zi == 0 ? W0 : zi == 1 ? W1 : zi == 2 ? W2 : W3;
    u16* T = zi == 0 ? T0 : zi == 1 ? T1 : zi == 2 ? T2 : T3;
    const int r0 = (lb & 15) * 64;           // K dim
    const int c0 = ((lb >> 4) & 15) * 64;    // N dim
#pragma unroll
    for (int i = 0; i < 4; ++i) {
        int ch = i * 256 + tid;
        int row = ch >> 4, cg = ch & 15;
        float4 x = *(const float4*)&W[(size_t)(r0 + row) * 1024 + c0 + cg * 4];
        tile[row][cg * 4 + 0] = x.x;
        tile[row][cg * 4 + 1] = x.y;
        tile[row][cg * 4 + 2] = x.z;
        tile[row][cg * 4 + 3] = x.w;
    }
    __syncthreads();
#pragma unroll
    for (int i = 0; i < 2; ++i) {
        int ch = i * 256 + tid;
        int orow = ch >> 3, ocg = ch & 7;
        u32x4 o;
#pragma unroll
        for (int j = 0; j < 4; ++j)
            o[j] = pack2bf(tile[ocg * 8 + 2 * j][orow], tile[ocg * 8 + 2 * j + 1][orow]);
        *(u32x4*)&T[(size_t)(c0 + orow) * 1024 + r0 + ocg * 8] = o;
    }
}

// ---------------------------------------------------------------------------
// Fused QKV projection GEMM, all-bf16, double-buffered global_load_lds.
// bid 0..127: Q (M=2048), 128..383: K (M=4096), 384..639: V (M=4096).
// 128x128 tile, BK=64, 4 waves, XCD-swizzled block order.
// V task writes TRANSPOSED output hvT[b*HID + ch][KLEN] via LDS transpose.
// ---------------------------------------------------------------------------
__device__ __forceinline__ void gemm_step128(
    const u16* __restrict__ As, const u16* __restrict__ Bs,
    int wr, int wc, int m, int g, f32x4 (*acc)[4])
{
#pragma unroll
    for (int kk = 0; kk < 64; kk += 32) {
        bf16x8 af[4], bfr[4];
#pragma unroll
        for (int mi = 0; mi < 4; ++mi) {
            int row = wr * 64 + mi * 16 + m;
            af[mi] = *(const bf16x8*)&As[(row * 64 + kk + g * 8) ^ ((row & 7) << 3)];
        }
#pragma unroll
        for (int ni = 0; ni < 4; ++ni) {
            int row = wc * 64 + ni * 16 + m;
            bfr[ni] = *(const bf16x8*)&Bs[(row * 64 + kk + g * 8) ^ ((row & 7) << 3)];
        }
#pragma unroll
        for (int mi = 0; mi < 4; ++mi)
#pragma unroll
            for (int ni = 0; ni < 4; ++ni)
                acc[mi][ni] = __builtin_amdgcn_mfma_f32_16x16x32_bf16(
                    af[mi], bfr[ni], acc[mi][ni], 0, 0, 0);
    }
}

__global__ __launch_bounds__(256) void qkv_gemm_kernel(
    const u16* __restrict__ Aq, const u16* __restrict__ Ak, const u16* __restrict__ Av,
    const u16* __restrict__ Bq, const u16* __restrict__ Bk, const u16* __restrict__ Bv,
    u16* __restrict__ hq, u16* __restrict__ hk, u16* __restrict__ hvT)
{
    __shared__ u32x4 lds[4096];              // 64KB: As0|Bs0|As1|Bs1 16KB each
    u16* As0 = (u16*)lds;
    u16* Bs0 = (u16*)(lds + 1024);
    u16* As1 = (u16*)(lds + 2048);
    u16* Bs1 = (u16*)(lds + 3072);

    const int i = blockIdx.x;                // 640 blocks
    const int bid = (i & 7) * 80 + (i >> 3); // XCD-contiguous chunks of 80
    const u16* A; const u16* Bt; u16* C; int lb, task;
    if (bid < 128)      { task = 0; A = Aq; Bt = Bq; C = hq; lb = bid; }
    else if (bid < 384) { task = 1; A = Ak; Bt = Bk; C = hk; lb = bid - 128; }
    else                { task = 2; A = Av; Bt = Bv; C = nullptr; lb = bid - 384; }
    const int m0 = (lb >> 3) * 128, n0 = (lb & 7) * 128;

    const int tid = threadIdx.x;
    const int lane = tid & 63, wv = tid >> 6;
    const int wr = wv >> 1, wc = wv & 1;
    const int m = lane & 15, g = lane >> 4;

    const u16* Ab = A  + (size_t)m0 * 1024;
    const u16* Bb = Bt + (size_t)n0 * 1024;

    f32x4 acc[4][4];
#pragma unroll
    for (int i2 = 0; i2 < 4; ++i2)
#pragma unroll
        for (int j = 0; j < 4; ++j) acc[i2][j] = zero4();

    stage64<128>(Ab, 1024, As0, tid);
    stage64<128>(Bb, 1024, Bs0, tid);
    __syncthreads();
#pragma unroll 1
    for (int k0 = 0; k0 < 1024; k0 += 128) {
        stage64<128>(Ab + k0 + 64, 1024, As1, tid);
        stage64<128>(Bb + k0 + 64, 1024, Bs1, tid);
        gemm_step128(As0, Bs0, wr, wc, m, g, acc);
        __syncthreads();
        if (k0 + 128 < 1024) {
            stage64<128>(Ab + k0 + 128, 1024, As0, tid);
            stage64<128>(Bb + k0 + 128, 1024, Bs0, tid);
        }
        gemm_step128(As1, Bs1, wr, wc, m, g, acc);
        __syncthreads();
    }

    if (task < 2) {
#pragma unroll
        for (int mi = 0; mi < 4; ++mi)
#pragma unroll
            for (int r = 0; r < 4; ++r) {
                int row = m0 + wr * 64 + mi * 16 + g * 4 + r;
#pragma unroll
                for (int ni = 0; ni < 4; ++ni) {
                    int col = n0 + wc * 64 + ni * 16 + m;
                    C[(size_t)row * HID + col] = f2bf(acc[mi][ni][r]);
                }
            }
    } else {
        // transposed epilogue -> hvT[b*HID + ch][KLEN]
        u16* T = (u16*)lds;                  // 128(ch) x 128(kv) bf16 = 32KB
#pragma unroll
        for (int mi = 0; mi < 4; ++mi)
#pragma unroll
            for (int ni = 0; ni < 4; ++ni)
#pragma unroll
                for (int r = 0; r < 4; ++r) {
                    int row = wr * 64 + mi * 16 + g * 4 + r;   // kv-local
                    int col = wc * 64 + ni * 16 + m;           // ch-local
                    T[col * 128 + ((((row >> 3) ^ (col & 7)) << 3) + (row & 7))] =
                        f2bf(acc[mi][ni][r]);
                }
        __syncthreads();
        const int b = m0 >> 11, kv0 = m0 & 2047;
#pragma unroll
        for (int it = 0; it < 8; ++it) {
            int idx = it * 256 + tid;
            int orow = idx >> 4, og = idx & 15;
            u32x4 x = *(const u32x4*)&T[orow * 128 + ((og ^ (orow & 7)) << 3)];
            *(u32x4*)&hvT[(size_t)(b * HID + n0 + orow) * KLEN + kv0 + og * 8] = x;
        }
    }
}

// ---------------------------------------------------------------------------
// Fused sigmoid-attention, kv-split = 2, double-buffered K/V staging.
// 1024 blocks (XCD-swizzled), 4 waves; wave owns 16 q rows x 1024 kv.
// Mask applied to P in-kernel (Ml tile).
// ---------------------------------------------------------------------------
__device__ __forceinline__ void attn_tile(
    const u16* __restrict__ Ks, const u16* __restrict__ Vt,
    const float* __restrict__ Mlc, u16* __restrict__ P,
    bf16x8 qf0, bf16x8 qf1, int m, int g, f32x4* o)
{
#pragma unroll
    for (int sub = 0; sub < 2; ++sub) {
#pragma unroll
        for (int t = 0; t < 2; ++t) {
            int kvr = sub * 32 + t * 16 + m;
            bf16x8 ak0 = *(const bf16x8*)&Ks[(kvr * 64 + g * 8) ^ ((kvr & 7) << 3)];
            bf16x8 ak1 = *(const bf16x8*)&Ks[(kvr * 64 + 32 + g * 8) ^ ((kvr & 7) << 3)];
            f32x4 s = zero4();
            s = __builtin_amdgcn_mfma_f32_16x16x32_bf16(ak0, qf0, s, 0, 0, 0);
            s = __builtin_amdgcn_mfma_f32_16x16x32_bf16(ak1, qf1, s, 0, 0, 0);
            // lane holds S^T[kv = sub*32 + t*16 + 4g + r][q = m]
            f32x4 mk = *(const f32x4*)&Mlc[sub * 32 + t * 16 + 4 * g];
            float p0 = mk[0] * __builtin_amdgcn_rcpf(1.0f + __expf(s[0] * -SCALE));
            float p1 = mk[1] * __builtin_amdgcn_rcpf(1.0f + __expf(s[1] * -SCALE));
            float p2 = mk[2] * __builtin_amdgcn_rcpf(1.0f + __expf(s[2] * -SCALE));
            float p3 = mk[3] * __builtin_amdgcn_rcpf(1.0f + __expf(s[3] * -SCALE));
            u32x2 pp = { cvtpk(p0, p1), cvtpk(p2, p3) };
            *(u32x2*)&P[m * 40 + t * 16 + 4 * g] = pp;    // P[q=m][j-local]
        }
        // same-wave roundtrip: lane reads P[q=m][8g..8g+7]
        bf16x8 pa = *(const bf16x8*)&P[m * 40 + 8 * g];
#pragma unroll
        for (int nt = 0; nt < 4; ++nt) {
            int d = 16 * nt + m;
            bf16x8 vt = *(const bf16x8*)&Vt[(d * 64 + sub * 32 + g * 8) ^ ((d & 7) << 3)];
            o[nt] = __builtin_amdgcn_mfma_f32_16x16x32_bf16(pa, vt, o[nt], 0, 0, 0);
        }
    }
}

__global__ __launch_bounds__(256) void attn_kernel(
    const u16* __restrict__ hq, const u16* __restrict__ hk,
    const u16* __restrict__ hvT, const int* __restrict__ amask,
    float* __restrict__ O0, float* __restrict__ O1)
{
    __shared__ u32x4 KsBuf[2][512];          // 2 x 8KB
    __shared__ u32x4 VtBuf[2][512];          // 2 x 8KB
    __shared__ __align__(16) float Ml[2][64];
    __shared__ __align__(16) u16 Pw[4][16 * 40];  // padded stride 40

    const int tid = threadIdx.x;
    const int lane = tid & 63, wv = tid >> 6;
    const int m = lane & 15, g = lane >> 4;
    const int li = blockIdx.x;               // 1024 blocks
    const int bid = (li & 7) * 128 + (li >> 3); // XCD-contiguous chunks of 128
    const int qt = bid & 15, h = (bid >> 4) & 15, z = bid >> 8;
    const int b = z >> 1, sp = z & 1;
    const int qrow0 = qt * 64 + wv * 16;
    float* Op = sp ? O1 : O0;
    u16* P = Pw[wv];
    u16* Ks0 = (u16*)KsBuf[0]; u16* Ks1 = (u16*)KsBuf[1];
    u16* Vt0 = (u16*)VtBuf[0]; u16* Vt1 = (u16*)VtBuf[1];

    const u16* qp = &hq[(size_t)(b * QLEN + qrow0 + m) * HID + h * HD + g * 8];
    bf16x8 qf0 = *(const bf16x8*)qp;
    bf16x8 qf1 = *(const bf16x8*)(qp + 32);

    const u16* kbase = hk + (size_t)(b * KLEN + sp * 1024) * HID + h * HD;
    const u16* vbase = hvT + (size_t)(b * HID + h * HD) * KLEN + sp * 1024;
    const int* mbase = amask + b * KLEN + sp * 1024;

    f32x4 o[4];
#pragma unroll
    for (int i = 0; i < 4; ++i) o[i] = zero4();

    // prologue: stage tile 0 into buf0
    stage64<64>(kbase, HID, Ks0, tid);
    stage64<64>(vbase, KLEN, Vt0, tid);
    if (tid < 64) Ml[0][tid] = (mbase[tid] != 0) ? 1.0f : 0.0f;
    __syncthreads();

#pragma unroll 1
    for (int it = 0; it < 16; it += 2) {
        stage64<64>(kbase + (size_t)(it + 1) * 64 * HID, HID, Ks1, tid);
        stage64<64>(vbase + (it + 1) * 64, KLEN, Vt1, tid);
        if (tid < 64) Ml[1][tid] = (mbase[(it + 1) * 64 + tid] != 0) ? 1.0f : 0.0f;
        attn_tile(Ks0, Vt0, Ml[0], P, qf0, qf1, m, g, o);
        __syncthreads();
        if (it + 2 < 16) {
            stage64<64>(kbase + (size_t)(it + 2) * 64 * HID, HID, Ks0, tid);
            stage64<64>(vbase + (it + 2) * 64, KLEN, Vt0, tid);
            if (tid < 64) Ml[0][tid] = (mbase[(it + 2) * 64 + tid] != 0) ? 1.0f : 0.0f;
        }
        attn_tile(Ks1, Vt1, Ml[1], P, qf0, qf1, m, g, o);
        __syncthreads();
    }
    // lane reg r holds O[q = 4g+r][d = 16nt+m]
#pragma unroll
    for (int nt = 0; nt < 4; ++nt)
#pragma unroll
        for (int r = 0; r < 4; ++r)
            Op[(size_t)(b * QLEN + qrow0 + 4 * g + r) * HID + h * HD + 16 * nt + m] =
                o[nt][r];
}

// ---------------------------------------------------------------------------
// Output projection: out = (O0+O1) @ Wo. 64x128 tile, grid (32,8) = 256 blocks.
// ---------------------------------------------------------------------------
__global__ __launch_bounds__(256) void oproj_kernel(
    const float* __restrict__ O0, const float* __restrict__ O1,
    const u16* __restrict__ Bt, float* __restrict__ out)
{
    __shared__ u32x4 lds[1536];              // As 8KB | Bs 16KB
    u16* As = (u16*)lds;
    u16* Bs = (u16*)(lds + 512);

    const int tid = threadIdx.x;
    const int lane = tid & 63, wv = tid >> 6;
    const int wr = wv >> 1, wc = wv & 1;
    const int m = lane & 15, g = lane >> 4;
    const int m0 = blockIdx.x * 64, n0 = blockIdx.y * 128;

    f32x4 acc[2][4];
#pragma unroll
    for (int i = 0; i < 2; ++i)
#pragma unroll
        for (int j = 0; j < 4; ++j) acc[i][j] = zero4();

    for (int k0 = 0; k0 < 1024; k0 += 64) {
        stage64<128>(Bt + (size_t)n0 * 1024 + k0, 1024, Bs, tid);
        // A: 64 rows x 8 granules = 512 chunks, reg-staged f32 sum -> bf16
#pragma unroll
        for (int c = 0; c < 2; ++c) {
            int idx = c * 256 + tid;
            int row = idx >> 3, cg = idx & 7;
            size_t off = (size_t)(m0 + row) * 1024 + k0 + cg * 8;
            float4 a0 = *(const float4*)&O0[off];
            float4 a1 = *(const float4*)&O0[off + 4];
            float4 b0 = *(const float4*)&O1[off];
            float4 b1 = *(const float4*)&O1[off + 4];
            u32x4 w;
            w[0] = pack2bf(a0.x + b0.x, a0.y + b0.y);
            w[1] = pack2bf(a0.z + b0.z, a0.w + b0.w);
            w[2] = pack2bf(a1.x + b1.x, a1.y + b1.y);
            w[3] = pack2bf(a1.z + b1.z, a1.w + b1.w);
            *(u32x4*)&As[(row * 64 + cg * 8) ^ ((row & 7) << 3)] = w;
        }
        __syncthreads();
#pragma unroll
        for (int kk = 0; kk < 64; kk += 32) {
            bf16x8 af[2], bfr[4];
#pragma unroll
            for (int mi = 0; mi < 2; ++mi) {
                int row = wr * 32 + mi * 16 + m;
                af[mi] = *(const bf16x8*)&As[(row * 64 + kk + g * 8) ^ ((row & 7) << 3)];
            }
#pragma unroll
            for (int ni = 0; ni < 4; ++ni) {
                int row = wc * 64 + ni * 16 + m;
                bfr[ni] = *(const bf16x8*)&Bs[(row * 64 + kk + g * 8) ^ ((row & 7) << 3)];
            }
#pragma unroll
            for (int mi = 0; mi < 2; ++mi)
#pragma unroll
                for (int ni = 0; ni < 4; ++ni)
                    acc[mi][ni] = __builtin_amdgcn_mfma_f32_16x16x32_bf16(
                        af[mi], bfr[ni], acc[mi][ni], 0, 0, 0);
        }
        __syncthreads();
    }
#pragma unroll
    for (int mi = 0; mi < 2; ++mi)
#pragma unroll
        for (int r = 0; r < 4; ++r) {
            int row = m0 + wr * 32 + mi * 16 + g * 4 + r;
#pragma unroll
            for (int ni = 0; ni < 4; ++ni) {
                int col = n0 + wc * 64 + ni * 16 + m;
                out[(size_t)row * HID + col] = acc[mi][ni][r];
            }
        }
}

// ---------------------------------------------------------------------------
extern "C" void kernel_launch(void* const* d_in, const int* in_sizes, int n_in,
                              void* d_out, int out_size, void* d_ws, size_t ws_size,
                              hipStream_t stream)
{
    const float* query = (const float*)d_in[0];
    const float* key   = (const float*)d_in[1];
    const float* value = (const float*)d_in[2];
    const int*   amask = (const int*)d_in[3];
    const float* Wq    = (const float*)d_in[4];
    const float* Wk    = (const float*)d_in[5];
    const float* Wv    = (const float*)d_in[6];
    const float* Wo    = (const float*)d_in[7];

    char* ws = (char*)d_ws;
    u16* wtq = (u16*)(ws + (0ull  << 20));   // 2MB
    u16* wtk = (u16*)(ws + (2ull  << 20));   // 2MB
    u16* wtv = (u16*)(ws + (4ull  << 20));   // 2MB
    u16* wto = (u16*)(ws + (6ull  << 20));   // 2MB
    u16* hq  = (u16*)(ws + (8ull  << 20));   // 4MB  bf16 [2048][1024]
    u16* hk  = (u16*)(ws + (12ull << 20));   // 8MB  bf16 [4096][1024]
    u16* hvT = (u16*)(ws + (20ull << 20));   // 8MB  bf16 [2048][2048] (b*HID+ch, kv)
    u16* qbf = (u16*)(ws + (28ull << 20));   // 4MB  bf16 [2048][1024]
    u16* kbf = (u16*)(ws + (32ull << 20));   // 8MB  bf16 [4096][1024]
    u16* vbf = (u16*)(ws + (40ull << 20));   // 8MB  bf16 [4096][1024]
    // O0/O1 alias qbf/kbf/vbf (dead after qkv_gemm)
    float* O0 = (float*)(ws + (28ull << 20)); // 8MB f32 [2048][1024]
    float* O1 = (float*)(ws + (36ull << 20)); // 8MB

    prep_kernel<<<dim3(6144), 256, 0, stream>>>(query, key, value, Wq, Wk, Wv, Wo,
                                                qbf, kbf, vbf, wtq, wtk, wtv, wto);
    qkv_gemm_kernel<<<dim3(640), 256, 0, stream>>>(qbf, kbf, vbf, wtq, wtk, wtv,
                                                   hq, hk, hvT);
    attn_kernel<<<dim3(1024), 256, 0, stream>>>(hq, hk, hvT, amask, O0, O1);
    oproj_kernel<<<dim3(32, 8), 256, 0, stream>>>(O0, O1, wto, (float*)d_out);
}